// Round 1
// baseline (3298.389 us; speedup 1.0000x reference)
//
#include <hip/hip_runtime.h>
#include <hip/hip_bf16.h>

// Problem constants
#define BB    4
#define TT    1024
#define CC    1024
#define HH    16
#define HSZ   64
#define DFF   4096
#define NTOK  (BB*TT)          // 4096
#define BHN   (BB*HH)          // 64

// ---------------- LayerNorm: one block per row (C=1024, 256 thr x float4) ----
__global__ __launch_bounds__(256)
void ln_k(const float* __restrict__ x, const float* __restrict__ g,
          const float* __restrict__ be, float* __restrict__ o)
{
    __shared__ float s1[4], s2[4];
    long row = blockIdx.x;
    const float4* xr = (const float4*)(x + row * CC);
    float4 v = xr[threadIdx.x];
    float a = v.x + v.y + v.z + v.w;
    float b = v.x*v.x + v.y*v.y + v.z*v.z + v.w*v.w;
    for (int off = 32; off > 0; off >>= 1) {
        a += __shfl_down(a, off);
        b += __shfl_down(b, off);
    }
    if ((threadIdx.x & 63) == 0) { s1[threadIdx.x >> 6] = a; s2[threadIdx.x >> 6] = b; }
    __syncthreads();
    float sum = s1[0] + s1[1] + s1[2] + s1[3];
    float sq  = s2[0] + s2[1] + s2[2] + s2[3];
    float mu  = sum * (1.0f / CC);
    float var = sq * (1.0f / CC) - mu * mu;
    float inv = rsqrtf(var + 1e-5f);
    float4 gg = ((const float4*)g)[threadIdx.x];
    float4 bb = ((const float4*)be)[threadIdx.x];
    float4 r;
    r.x = (v.x - mu) * inv * gg.x + bb.x;
    r.y = (v.y - mu) * inv * gg.y + bb.y;
    r.z = (v.z - mu) * inv * gg.z + bb.z;
    r.w = (v.w - mu) * inv * gg.w + bb.w;
    ((float4*)(o + row * CC))[threadIdx.x] = r;
}

// ---------------- Softmax: one block per row of 1024, in place ---------------
__global__ __launch_bounds__(256)
void softmax_k(float* __restrict__ w)
{
    __shared__ float sm[4];
    long row = blockIdx.x;
    float4* wr = (float4*)(w + row * 1024);
    float4 v = wr[threadIdx.x];
    float m = fmaxf(fmaxf(v.x, v.y), fmaxf(v.z, v.w));
    for (int off = 32; off > 0; off >>= 1) m = fmaxf(m, __shfl_down(m, off));
    if ((threadIdx.x & 63) == 0) sm[threadIdx.x >> 6] = m;
    __syncthreads();
    m = fmaxf(fmaxf(sm[0], sm[1]), fmaxf(sm[2], sm[3]));
    __syncthreads();   // before reusing sm
    float4 e;
    e.x = __expf(v.x - m); e.y = __expf(v.y - m);
    e.z = __expf(v.z - m); e.w = __expf(v.w - m);
    float s = e.x + e.y + e.z + e.w;
    for (int off = 32; off > 0; off >>= 1) s += __shfl_down(s, off);
    if ((threadIdx.x & 63) == 0) sm[threadIdx.x >> 6] = s;
    __syncthreads();
    s = sm[0] + sm[1] + sm[2] + sm[3];
    float r = 1.0f / s;
    e.x *= r; e.y *= r; e.z *= r; e.w *= r;
    wr[threadIdx.x] = e;
}

// ---------------- Generic tiled f32 GEMM -------------------------------------
// C = A[M,K] @ B[K,N]  (+ scale, bias, relu, residual), 256 threads,
// BMxBN tile, each thread BM/16 x BN/16 outputs at stride-16 (coalesced).
enum { BL_ROW = 0, BL_TRANS = 1, BL_QKV = 2 };
enum { OL_PLAIN = 0, OL_QKV = 1, OL_HEADCAT = 2 };
constexpr int EBIAS = 1, ERELU = 2, ERES = 4, ESCALE = 8;

template<int BM, int BN, int BL, int OL, int EPI>
__global__ __launch_bounds__(256)
void gemm_k(const float* __restrict__ A, const float* __restrict__ Bm,
            const float* __restrict__ bias, const float* __restrict__ res,
            float* __restrict__ C, int M, int N, int K,
            long sA, long sB, long sC, float scale)
{
    constexpr int BK = 16;
    constexpr int TM = BM / 16, TN = BN / 16;
    __shared__ float As[BK][BM + 1];
    __shared__ float Bs[BK][BN + 1];
    const int tid = threadIdx.x;
    const int tx = tid & 15, ty = tid >> 4;
    const int bh = blockIdx.z;
    const float* Ap = A + (long)bh * sA;
    const float* Bp = Bm + (long)bh * sB;
    float* Cp = C + (long)bh * sC;
    const int row0 = blockIdx.y * BM, col0 = blockIdx.x * BN;

    float acc[TM][TN];
#pragma unroll
    for (int i = 0; i < TM; i++)
#pragma unroll
        for (int j = 0; j < TN; j++) acc[i][j] = 0.0f;

    for (int k0 = 0; k0 < K; k0 += BK) {
        // A tile: BM x BK, coalesced 16-wide along K
#pragma unroll
        for (int i = 0; i < BM / 16; i++) {
            int m = (tid >> 4) + 16 * i;
            As[tid & 15][m] = Ap[(long)(row0 + m) * K + (k0 + (tid & 15))];
        }
        // B tile: BK x BN
        if (BL == BL_TRANS) {
#pragma unroll
            for (int i = 0; i < BN / 16; i++) {
                int n = (tid >> 4) + 16 * i;
                Bs[tid & 15][n] = Bp[(long)(col0 + n) * K + (k0 + (tid & 15))];
            }
        } else {
            constexpr int RP = 256 / BN;   // tile rows loaded per pass
#pragma unroll
            for (int i = 0; i < BK / RP; i++) {
                int n  = tid % BN;
                int kk = tid / BN + RP * i;
                int gj = col0 + n, gk = k0 + kk;
                Bs[kk][n] = (BL == BL_QKV)
                    ? Bp[(long)(gj >> 6) * (CC * HSZ) + (long)gk * HSZ + (gj & 63)]
                    : Bp[(long)gk * N + gj];
            }
        }
        __syncthreads();
#pragma unroll
        for (int kk = 0; kk < BK; kk++) {
            float a[TM], b[TN];
#pragma unroll
            for (int i = 0; i < TM; i++) a[i] = As[kk][ty + 16 * i];
#pragma unroll
            for (int j = 0; j < TN; j++) b[j] = Bs[kk][tx + 16 * j];
#pragma unroll
            for (int i = 0; i < TM; i++)
#pragma unroll
                for (int j = 0; j < TN; j++) acc[i][j] = fmaf(a[i], b[j], acc[i][j]);
        }
        __syncthreads();
    }
    // epilogue
#pragma unroll
    for (int i = 0; i < TM; i++) {
        int r = row0 + ty + 16 * i;
#pragma unroll
        for (int j = 0; j < TN; j++) {
            int cgl = col0 + tx + 16 * j;
            float val = acc[i][j];
            if (EPI & ESCALE) val *= scale;
            if (EPI & EBIAS)  val += bias[cgl];
            if (EPI & ERELU)  val = fmaxf(val, 0.0f);
            if (EPI & ERES)   val += res[(long)r * N + cgl];
            long idx;
            if (OL == OL_PLAIN)
                idx = (long)r * N + cgl;
            else if (OL == OL_QKV)   // r=b*T+t, cgl=h*64+d -> [B,H,T,HS]
                idx = ((long)((r >> 10) * HH + (cgl >> 6))) * (TT * HSZ)
                      + (long)(r & 1023) * HSZ + (cgl & 63);
            else                     // HEADCAT: bh batch, r=t, cgl=d -> [B,T,C]
                idx = ((long)(bh >> 4) * TT + r) * CC + (long)(bh & 15) * HSZ + cgl;
            Cp[idx] = val;
        }
    }
}

// ---------------- launch -----------------------------------------------------
extern "C" void kernel_launch(void* const* d_in, const int* in_sizes, int n_in,
                              void* d_out, int out_size, void* d_ws, size_t ws_size,
                              hipStream_t stream)
{
    const float* x      = (const float*)d_in[0];
    const float* wq     = (const float*)d_in[1];
    const float* wk     = (const float*)d_in[2];
    const float* wv     = (const float*)d_in[3];
    const float* w_proj = (const float*)d_in[4];
    const float* b_proj = (const float*)d_in[5];
    const float* w1     = (const float*)d_in[6];
    const float* b1     = (const float*)d_in[7];
    const float* w2     = (const float*)d_in[8];
    const float* b2     = (const float*)d_in[9];
    const float* g1     = (const float*)d_in[10];
    const float* be1    = (const float*)d_in[11];
    const float* g2     = (const float*)d_in[12];
    const float* be2    = (const float*)d_in[13];

    float* out_x = (float*)d_out;                  // [B,T,C] = 4,194,304
    float* wei   = out_x + (long)NTOK * CC;        // [B,H,T,T] = 67,108,864

    // workspace (floats), total 32M floats = 128 MiB
    float* ws  = (float*)d_ws;
    const long SZ = (long)NTOK * CC;               // 4,194,304
    float* h    = ws;                              // LN1 out, later attn_concat
    float* q_   = ws + SZ;
    float* k_   = ws + 2 * SZ;
    float* v_   = ws + 3 * SZ;
    float* a1   = ws + 4 * SZ;                     // [4096,4096]
    float* attn = h;                               // reuse (h dead after QKV)
    float* x1   = q_;                              // reuse (q dead after PV)
    float* h2   = k_;                              // reuse (k dead after PV)

    // 1. h = LN(x, g1, be1)
    ln_k<<<NTOK, 256, 0, stream>>>(x, g1, be1, h);

    // 2. q,k,v = h @ Wq/Wk/Wv  -> [B,H,T,HS]
    dim3 gQKV(CC / 128, NTOK / 128, 1);
    gemm_k<128,128,BL_QKV,OL_QKV,0><<<gQKV, 256, 0, stream>>>(
        h, wq, nullptr, nullptr, q_, NTOK, CC, CC, 0, 0, 0, 0.f);
    gemm_k<128,128,BL_QKV,OL_QKV,0><<<gQKV, 256, 0, stream>>>(
        h, wk, nullptr, nullptr, k_, NTOK, CC, CC, 0, 0, 0, 0.f);
    gemm_k<128,128,BL_QKV,OL_QKV,0><<<gQKV, 256, 0, stream>>>(
        h, wv, nullptr, nullptr, v_, NTOK, CC, CC, 0, 0, 0, 0.f);

    // 3. scores = q @ k^T * (HS^-0.5), batched over 64 (b,h)
    gemm_k<128,128,BL_TRANS,OL_PLAIN,ESCALE><<<dim3(TT/128, TT/128, BHN), 256, 0, stream>>>(
        q_, k_, nullptr, nullptr, wei, TT, TT, HSZ,
        (long)TT * HSZ, (long)TT * HSZ, (long)TT * TT, 0.125f);

    // 4. softmax rows (in place in d_out's wei region)
    softmax_k<<<BHN * TT, 256, 0, stream>>>(wei);

    // 5. attn_concat = wei @ v  -> [B,T,C]
    gemm_k<128,64,BL_ROW,OL_HEADCAT,0><<<dim3(1, TT/128, BHN), 256, 0, stream>>>(
        wei, v_, nullptr, nullptr, attn, TT, HSZ, TT,
        (long)TT * TT, (long)TT * HSZ, 0, 0.f);

    // 6. x1 = x + attn_concat @ w_proj + b_proj
    gemm_k<128,128,BL_ROW,OL_PLAIN,EBIAS|ERES><<<dim3(CC/128, NTOK/128, 1), 256, 0, stream>>>(
        attn, w_proj, b_proj, x, x1, NTOK, CC, CC, 0, 0, 0, 0.f);

    // 7. h2 = LN(x1, g2, be2)
    ln_k<<<NTOK, 256, 0, stream>>>(x1, g2, be2, h2);

    // 8. a1 = relu(h2 @ w1 + b1)
    gemm_k<128,128,BL_ROW,OL_PLAIN,EBIAS|ERELU><<<dim3(DFF/128, NTOK/128, 1), 256, 0, stream>>>(
        h2, w1, b1, nullptr, a1, NTOK, DFF, CC, 0, 0, 0, 0.f);

    // 9. out = x1 + a1 @ w2 + b2
    gemm_k<128,128,BL_ROW,OL_PLAIN,EBIAS|ERES><<<dim3(CC/128, NTOK/128, 1), 256, 0, stream>>>(
        a1, w2, b2, x1, out_x, NTOK, CC, DFF, 0, 0, 0, 0.f);
}

// Round 2
// 533.950 us; speedup vs baseline: 6.1773x; 6.1773x over previous
//
#include <hip/hip_runtime.h>
#include <hip/hip_bf16.h>

// Problem constants
#define BB    4
#define TT    1024
#define CC    1024
#define HH    16
#define HSZ   64
#define DFF   4096
#define NTOK  (BB*TT)          // 4096
#define BHN   (BB*HH)          // 64

typedef __attribute__((ext_vector_type(8))) short bf16x8;
typedef __attribute__((ext_vector_type(4))) float f32x4;

__device__ __forceinline__ ushort f2b(float v) {
    union { float f; unsigned u; } c; c.f = v;
    unsigned r = c.u + 0x7fffu + ((c.u >> 16) & 1u);   // RNE
    return (ushort)(r >> 16);
}
__device__ __forceinline__ void stv(float* p, float v)  { *p = v; }
__device__ __forceinline__ void stv(ushort* p, float v) { *p = f2b(v); }

__device__ __forceinline__ void gload16(const void* g, void* l) {
    __builtin_amdgcn_global_load_lds(
        (const __attribute__((address_space(1))) void*)g,
        (__attribute__((address_space(3))) void*)l, 16, 0, 0);
}

// ---------------- LayerNorm: f32 in -> bf16 out ------------------------------
__global__ __launch_bounds__(256)
void ln_k(const float* __restrict__ x, const float* __restrict__ g,
          const float* __restrict__ be, ushort* __restrict__ o)
{
    __shared__ float s1[4], s2[4];
    long row = blockIdx.x;
    const float4* xr = (const float4*)(x + row * CC);
    float4 v = xr[threadIdx.x];
    float a = v.x + v.y + v.z + v.w;
    float b = v.x*v.x + v.y*v.y + v.z*v.z + v.w*v.w;
    for (int off = 32; off > 0; off >>= 1) {
        a += __shfl_down(a, off);
        b += __shfl_down(b, off);
    }
    if ((threadIdx.x & 63) == 0) { s1[threadIdx.x >> 6] = a; s2[threadIdx.x >> 6] = b; }
    __syncthreads();
    float sum = s1[0] + s1[1] + s1[2] + s1[3];
    float sq  = s2[0] + s2[1] + s2[2] + s2[3];
    float mu  = sum * (1.0f / CC);
    float var = sq * (1.0f / CC) - mu * mu;
    float inv = rsqrtf(var + 1e-5f);
    float4 gg = ((const float4*)g)[threadIdx.x];
    float4 bb = ((const float4*)be)[threadIdx.x];
    ushort4 r;
    r.x = f2b((v.x - mu) * inv * gg.x + bb.x);
    r.y = f2b((v.y - mu) * inv * gg.y + bb.y);
    r.z = f2b((v.z - mu) * inv * gg.z + bb.z);
    r.w = f2b((v.w - mu) * inv * gg.w + bb.w);
    ((ushort4*)(o + row * CC))[threadIdx.x] = r;
}

// ---------------- Softmax: one block per row of 1024, in place (f32) ---------
__global__ __launch_bounds__(256)
void softmax_k(float* __restrict__ w)
{
    __shared__ float sm[4];
    long row = blockIdx.x;
    float4* wr = (float4*)(w + row * 1024);
    float4 v = wr[threadIdx.x];
    float m = fmaxf(fmaxf(v.x, v.y), fmaxf(v.z, v.w));
    for (int off = 32; off > 0; off >>= 1) m = fmaxf(m, __shfl_down(m, off));
    if ((threadIdx.x & 63) == 0) sm[threadIdx.x >> 6] = m;
    __syncthreads();
    m = fmaxf(fmaxf(sm[0], sm[1]), fmaxf(sm[2], sm[3]));
    __syncthreads();
    float4 e;
    e.x = __expf(v.x - m); e.y = __expf(v.y - m);
    e.z = __expf(v.z - m); e.w = __expf(v.w - m);
    float s = e.x + e.y + e.z + e.w;
    for (int off = 32; off > 0; off >>= 1) s += __shfl_down(s, off);
    if ((threadIdx.x & 63) == 0) sm[threadIdx.x >> 6] = s;
    __syncthreads();
    s = sm[0] + sm[1] + sm[2] + sm[3];
    float r = 1.0f / s;
    e.x *= r; e.y *= r; e.z *= r; e.w *= r;
    wr[threadIdx.x] = e;
}

// ---------------- Transposed f32 -> bf16 convert (weights) -------------------
// src [batch][R][Cc] f32 -> dst [batch][Cc][R] bf16
__global__ __launch_bounds__(256)
void tcvt_k(const float* __restrict__ src, ushort* __restrict__ dst, int R, int Cc)
{
    __shared__ float t[32][33];
    const long bz = blockIdx.z;
    src += bz * (long)R * Cc;
    dst += bz * (long)R * Cc;
    int r0 = blockIdx.y * 32, c0 = blockIdx.x * 32;
    int tx = threadIdx.x & 31, ty = threadIdx.x >> 5;   // ty: 0..7
#pragma unroll
    for (int i = 0; i < 4; i++)
        t[ty + 8*i][tx] = src[(long)(r0 + ty + 8*i) * Cc + c0 + tx];
    __syncthreads();
#pragma unroll
    for (int i = 0; i < 4; i++)
        dst[(long)(c0 + ty + 8*i) * R + r0 + tx] = f2b(t[tx][ty + 8*i]);
}

// ---------------- bf16 MFMA GEMM ---------------------------------------------
// C[M,N] = A[M,K] @ Bt[N,K]^T  (A row-major, Bt row-major = B^T)
// 256 threads = 4 waves arranged WM x WN; BK=64; 16x16x32 bf16 MFMA.
enum { OL_PLAIN = 0, OL_QKV = 1, OL_VT = 2, OL_HEADCAT = 3 };
constexpr int EBIAS = 1, ERELU = 2, ERES = 4, ESCALE = 8;

template<int BM, int BN, int WM, int WN, int OL, int EPI, typename AT, typename OutT>
__global__ __launch_bounds__(256)
void mgemm_k(const AT* __restrict__ A, const ushort* __restrict__ Bt,
             const float* __restrict__ bias, const float* __restrict__ res,
             OutT* __restrict__ C, int M, int N, int K,
             long sA, long sB, long sC, float scale)
{
    constexpr int BK = 64;
    constexpr int FM = BM / WM / 16, FN = BN / WN / 16;
    __shared__ ushort As[BM * BK];
    __shared__ ushort Bs[BN * BK];
    const int tid = threadIdx.x;
    const int w = tid >> 6, l = tid & 63;
    const int wr = w / WN, wc = w % WN;
    const int l15 = l & 15, l4 = l >> 4;
    const int bh = blockIdx.z;
    const AT*     Ap = A  + (long)bh * sA + (long)(blockIdx.y * BM) * K;
    const ushort* Bp = Bt + (long)bh * sB + (long)(blockIdx.x * BN) * K;

    f32x4 acc[FM][FN];
#pragma unroll
    for (int m = 0; m < FM; m++)
#pragma unroll
        for (int n = 0; n < FN; n++) acc[m][n] = (f32x4){0.f, 0.f, 0.f, 0.f};

    const int arow = tid >> 3;   // 0..31 (row within 32-row staging round)
    const int achk = tid & 7;    // 16B chunk within 128B row

    for (int k0 = 0; k0 < K; k0 += BK) {
        // ---- stage A tile (BM x 64 bf16) ----
        if constexpr (sizeof(AT) == 2) {
#pragma unroll
            for (int i = 0; i < BM / 32; i++)
                gload16(Ap + (long)(i*32 + arow) * K + k0 + achk*8,
                        &As[(i*32 + w*8) * BK]);
        } else {
            // A is f32: reg-stage + convert (PV path reads f32 probs)
#pragma unroll
            for (int i = 0; i < BM / 16; i++) {
                int id = i * 256 + tid;
                int r = id >> 4, c4 = id & 15;
                float4 v = *(const float4*)&Ap[(long)r * K + k0 + c4*4];
                ushort4 u; u.x = f2b(v.x); u.y = f2b(v.y); u.z = f2b(v.z); u.w = f2b(v.w);
                *(ushort4*)&As[r * BK + c4*4] = u;
            }
        }
        // ---- stage B tile (BN x 64 bf16) ----
#pragma unroll
        for (int i = 0; i < BN / 32; i++)
            gload16(Bp + (long)(i*32 + arow) * K + k0 + achk*8,
                    &Bs[(i*32 + w*8) * BK]);
        __syncthreads();
        // ---- MFMA ----
#pragma unroll
        for (int kk = 0; kk < 2; kk++) {
            const int ko = kk*32 + l4*8;
            bf16x8 af[FM], bfr[FN];
#pragma unroll
            for (int m = 0; m < FM; m++)
                af[m] = *(const bf16x8*)&As[(wr*(BM/WM) + m*16 + l15) * BK + ko];
#pragma unroll
            for (int n = 0; n < FN; n++)
                bfr[n] = *(const bf16x8*)&Bs[(wc*(BN/WN) + n*16 + l15) * BK + ko];
#pragma unroll
            for (int m = 0; m < FM; m++)
#pragma unroll
                for (int n = 0; n < FN; n++)
                    acc[m][n] = __builtin_amdgcn_mfma_f32_16x16x32_bf16(
                        af[m], bfr[n], acc[m][n], 0, 0, 0);
        }
        __syncthreads();
    }

    // ---- epilogue ----
#pragma unroll
    for (int m = 0; m < FM; m++) {
        int rbase = blockIdx.y*BM + wr*(BM/WM) + m*16 + l4*4;
#pragma unroll
        for (int n = 0; n < FN; n++) {
            int col = blockIdx.x*BN + wc*(BN/WN) + n*16 + l15;
#pragma unroll
            for (int r = 0; r < 4; r++) {
                int row = rbase + r;
                float v = acc[m][n][r];
                if (EPI & ESCALE) v *= scale;
                if (EPI & EBIAS)  v += bias[col];
                if (EPI & ERELU)  v = fmaxf(v, 0.f);
                if (EPI & ERES)   v += res[(long)row * N + col];
                long idx;
                if (OL == OL_PLAIN)
                    idx = (long)row * N + col;
                else if (OL == OL_QKV)      // row=b*T+t, col=h*64+d -> [B,H,T,HS]
                    idx = ((long)((row >> 10) * HH + (col >> 6))) * 65536
                          + (long)(row & 1023) * 64 + (col & 63);
                else if (OL == OL_VT)       // -> [B,H,HS,T]
                    idx = ((long)((row >> 10) * HH + (col >> 6))) * 65536
                          + (long)(col & 63) * 1024 + (row & 1023);
                else                        // HEADCAT: z=bh, row=t, col=d -> [B,T,C]
                    idx = ((long)(bh >> 4) * TT + row) * CC + (long)(bh & 15) * HSZ + col;
                stv(&C[(long)bh * sC + idx], v);
            }
        }
    }
}

// ---------------- launch -----------------------------------------------------
extern "C" void kernel_launch(void* const* d_in, const int* in_sizes, int n_in,
                              void* d_out, int out_size, void* d_ws, size_t ws_size,
                              hipStream_t stream)
{
    const float* x      = (const float*)d_in[0];
    const float* wq     = (const float*)d_in[1];
    const float* wk     = (const float*)d_in[2];
    const float* wv     = (const float*)d_in[3];
    const float* w_proj = (const float*)d_in[4];
    const float* b_proj = (const float*)d_in[5];
    const float* w1     = (const float*)d_in[6];
    const float* b1     = (const float*)d_in[7];
    const float* w2     = (const float*)d_in[8];
    const float* b2     = (const float*)d_in[9];
    const float* g1     = (const float*)d_in[10];
    const float* be1    = (const float*)d_in[11];
    const float* g2     = (const float*)d_in[12];
    const float* be2    = (const float*)d_in[13];

    float* out_x = (float*)d_out;                  // [B,T,C]
    float* wei   = out_x + (long)NTOK * CC;        // [B,H,T,T] f32

    // workspace layout (ushort elements), total 120 MiB
    const long MEL = 1 << 20;
    ushort* ws16 = (ushort*)d_ws;
    ushort* h    = ws16;                 // [4096,1024] bf16 (LN1 out)
    ushort* q_   = ws16 + 4*MEL;         // [B,H,T,HS]
    ushort* k_   = ws16 + 8*MEL;         // [B,H,T,HS]
    ushort* vt   = ws16 + 12*MEL;        // [B,H,HS,T]
    ushort* attn = ws16 + 16*MEL;        // [4096,1024] bf16
    ushort* h2   = ws16 + 20*MEL;        // [4096,1024] bf16 (LN2 out)
    ushort* a1   = ws16 + 24*MEL;        // [4096,4096] bf16
    ushort* wqt  = ws16 + 40*MEL;        // [1024,1024] bf16 (B^T)
    ushort* wkt  = ws16 + 41*MEL;
    ushort* wvt  = ws16 + 42*MEL;
    ushort* wpT  = ws16 + 43*MEL;
    ushort* w1T  = ws16 + 44*MEL;        // [4096,1024]
    ushort* w2T  = ws16 + 48*MEL;        // [1024,4096]
    float*  x1   = (float*)(ws16 + 52*MEL);  // [4096,1024] f32

    // weight conversions (transposed to B^T bf16)
    tcvt_k<<<dim3(2, 32, 16),  256, 0, stream>>>(wq,     wqt, 1024, 64);
    tcvt_k<<<dim3(2, 32, 16),  256, 0, stream>>>(wk,     wkt, 1024, 64);
    tcvt_k<<<dim3(2, 32, 16),  256, 0, stream>>>(wv,     wvt, 1024, 64);
    tcvt_k<<<dim3(32, 32, 1),  256, 0, stream>>>(w_proj, wpT, 1024, 1024);
    tcvt_k<<<dim3(128, 32, 1), 256, 0, stream>>>(w1,     w1T, 1024, 4096);
    tcvt_k<<<dim3(32, 128, 1), 256, 0, stream>>>(w2,     w2T, 4096, 1024);

    // 1. h = LN(x)
    ln_k<<<NTOK, 256, 0, stream>>>(x, g1, be1, h);

    // 2. q,k,v projections
    mgemm_k<128,128,2,2,OL_QKV,0,ushort,ushort><<<dim3(8,32,1), 256, 0, stream>>>(
        h, wqt, nullptr, nullptr, q_, NTOK, CC, CC, 0,0,0, 0.f);
    mgemm_k<128,128,2,2,OL_QKV,0,ushort,ushort><<<dim3(8,32,1), 256, 0, stream>>>(
        h, wkt, nullptr, nullptr, k_, NTOK, CC, CC, 0,0,0, 0.f);
    mgemm_k<128,128,2,2,OL_VT,0,ushort,ushort><<<dim3(8,32,1), 256, 0, stream>>>(
        h, wvt, nullptr, nullptr, vt, NTOK, CC, CC, 0,0,0, 0.f);

    // 3. scores = q @ k^T * 0.125  -> wei (f32, d_out)
    mgemm_k<128,128,2,2,OL_PLAIN,ESCALE,ushort,float><<<dim3(8,8,64), 256, 0, stream>>>(
        q_, k_, nullptr, nullptr, wei, TT, TT, HSZ,
        65536L, 65536L, (long)TT*TT, 0.125f);

    // 4. softmax in place
    softmax_k<<<BHN * TT, 256, 0, stream>>>(wei);

    // 5. attn = wei @ v (A f32 reg-staged-cvt), headcat -> [B,T,C] bf16
    mgemm_k<128,64,2,2,OL_HEADCAT,0,float,ushort><<<dim3(1,8,64), 256, 0, stream>>>(
        wei, vt, nullptr, nullptr, attn, TT, HSZ, TT,
        (long)TT*TT, 65536L, 0L, 0.f);

    // 6. x1 = x + attn @ w_proj + b_proj  (f32)
    mgemm_k<128,128,2,2,OL_PLAIN,EBIAS|ERES,ushort,float><<<dim3(8,32,1), 256, 0, stream>>>(
        attn, wpT, b_proj, x, x1, NTOK, CC, CC, 0,0,0, 0.f);

    // 7. h2 = LN(x1)
    ln_k<<<NTOK, 256, 0, stream>>>(x1, g2, be2, h2);

    // 8. a1 = relu(h2 @ w1 + b1)  bf16
    mgemm_k<128,128,2,2,OL_PLAIN,EBIAS|ERELU,ushort,ushort><<<dim3(32,32,1), 256, 0, stream>>>(
        h2, w1T, b1, nullptr, a1, NTOK, DFF, CC, 0,0,0, 0.f);

    // 9. out = x1 + a1 @ w2 + b2  (f32)
    mgemm_k<128,128,2,2,OL_PLAIN,EBIAS|ERES,ushort,float><<<dim3(8,32,1), 256, 0, stream>>>(
        a1, w2T, b2, x1, out_x, NTOK, CC, DFF, 0,0,0, 0.f);
}

// Round 3
// 462.820 us; speedup vs baseline: 7.1267x; 1.1537x over previous
//
#include <hip/hip_runtime.h>
#include <hip/hip_bf16.h>

// Problem constants
#define BB    4
#define TT    1024
#define CC    1024
#define HH    16
#define HSZ   64
#define DFF   4096
#define NTOK  (BB*TT)          // 4096
#define BHN   (BB*HH)          // 64

typedef __attribute__((ext_vector_type(8))) short bf16x8;
typedef __attribute__((ext_vector_type(4))) float f32x4;

__device__ __forceinline__ ushort f2b(float v) {
    union { float f; unsigned u; } c; c.f = v;
    unsigned r = c.u + 0x7fffu + ((c.u >> 16) & 1u);   // RNE
    return (ushort)(r >> 16);
}
__device__ __forceinline__ void stv(float* p, float v)  { *p = v; }
__device__ __forceinline__ void stv(ushort* p, float v) { *p = f2b(v); }

__device__ __forceinline__ void gload16(const void* g, void* l) {
    __builtin_amdgcn_global_load_lds(
        (const __attribute__((address_space(1))) void*)g,
        (__attribute__((address_space(3))) void*)l, 16, 0, 0);
}

// ---------------- LayerNorm: f32 in -> bf16 out ------------------------------
__global__ __launch_bounds__(256)
void ln_k(const float* __restrict__ x, const float* __restrict__ g,
          const float* __restrict__ be, ushort* __restrict__ o)
{
    __shared__ float s1[4], s2[4];
    long row = blockIdx.x;
    const float4* xr = (const float4*)(x + row * CC);
    float4 v = xr[threadIdx.x];
    float a = v.x + v.y + v.z + v.w;
    float b = v.x*v.x + v.y*v.y + v.z*v.z + v.w*v.w;
    for (int off = 32; off > 0; off >>= 1) {
        a += __shfl_down(a, off);
        b += __shfl_down(b, off);
    }
    if ((threadIdx.x & 63) == 0) { s1[threadIdx.x >> 6] = a; s2[threadIdx.x >> 6] = b; }
    __syncthreads();
    float sum = s1[0] + s1[1] + s1[2] + s1[3];
    float sq  = s2[0] + s2[1] + s2[2] + s2[3];
    float mu  = sum * (1.0f / CC);
    float var = sq * (1.0f / CC) - mu * mu;
    float inv = rsqrtf(var + 1e-5f);
    float4 gg = ((const float4*)g)[threadIdx.x];
    float4 bb = ((const float4*)be)[threadIdx.x];
    ushort4 r;
    r.x = f2b((v.x - mu) * inv * gg.x + bb.x);
    r.y = f2b((v.y - mu) * inv * gg.y + bb.y);
    r.z = f2b((v.z - mu) * inv * gg.z + bb.z);
    r.w = f2b((v.w - mu) * inv * gg.w + bb.w);
    ((ushort4*)(o + row * CC))[threadIdx.x] = r;
}

// ---------------- Transposed f32 -> bf16 convert (weights) -------------------
__global__ __launch_bounds__(256)
void tcvt_k(const float* __restrict__ src, ushort* __restrict__ dst, int R, int Cc)
{
    __shared__ float t[32][33];
    const long bz = blockIdx.z;
    src += bz * (long)R * Cc;
    dst += bz * (long)R * Cc;
    int r0 = blockIdx.y * 32, c0 = blockIdx.x * 32;
    int tx = threadIdx.x & 31, ty = threadIdx.x >> 5;
#pragma unroll
    for (int i = 0; i < 4; i++)
        t[ty + 8*i][tx] = src[(long)(r0 + ty + 8*i) * Cc + c0 + tx];
    __syncthreads();
#pragma unroll
    for (int i = 0; i < 4; i++)
        dst[(long)(c0 + ty + 8*i) * R + r0 + tx] = f2b(t[tx][ty + 8*i]);
}

// ---------------- bf16 MFMA GEMM ---------------------------------------------
enum { OL_PLAIN = 0, OL_QKV = 1, OL_VT = 2 };
constexpr int EBIAS = 1, ERELU = 2, ERES = 4, ESCALE = 8;

template<int BM, int BN, int WM, int WN, int OL, int EPI, typename OutT>
__global__ __launch_bounds__(256)
void mgemm_k(const ushort* __restrict__ A, const ushort* __restrict__ Bt,
             const float* __restrict__ bias, const float* __restrict__ res,
             OutT* __restrict__ C, int M, int N, int K,
             long sA, long sB, long sC, float scale)
{
    constexpr int BK = 64;
    constexpr int FM = BM / WM / 16, FN = BN / WN / 16;
    __shared__ ushort As[BM * BK];
    __shared__ ushort Bs[BN * BK];
    const int tid = threadIdx.x;
    const int w = tid >> 6, l = tid & 63;
    const int wr = w / WN, wc = w % WN;
    const int l15 = l & 15, l4 = l >> 4;
    const int bh = blockIdx.z;
    const ushort* Ap = A  + (long)bh * sA + (long)(blockIdx.y * BM) * K;
    const ushort* Bp = Bt + (long)bh * sB + (long)(blockIdx.x * BN) * K;

    f32x4 acc[FM][FN];
#pragma unroll
    for (int m = 0; m < FM; m++)
#pragma unroll
        for (int n = 0; n < FN; n++) acc[m][n] = (f32x4){0.f, 0.f, 0.f, 0.f};

    const int arow = tid >> 3;
    const int achk = tid & 7;

    for (int k0 = 0; k0 < K; k0 += BK) {
#pragma unroll
        for (int i = 0; i < BM / 32; i++)
            gload16(Ap + (long)(i*32 + arow) * K + k0 + achk*8,
                    &As[(i*32 + w*8) * BK]);
#pragma unroll
        for (int i = 0; i < BN / 32; i++)
            gload16(Bp + (long)(i*32 + arow) * K + k0 + achk*8,
                    &Bs[(i*32 + w*8) * BK]);
        __syncthreads();
#pragma unroll
        for (int kk = 0; kk < 2; kk++) {
            const int ko = kk*32 + l4*8;
            bf16x8 af[FM], bfr[FN];
#pragma unroll
            for (int m = 0; m < FM; m++)
                af[m] = *(const bf16x8*)&As[(wr*(BM/WM) + m*16 + l15) * BK + ko];
#pragma unroll
            for (int n = 0; n < FN; n++)
                bfr[n] = *(const bf16x8*)&Bs[(wc*(BN/WN) + n*16 + l15) * BK + ko];
#pragma unroll
            for (int m = 0; m < FM; m++)
#pragma unroll
                for (int n = 0; n < FN; n++)
                    acc[m][n] = __builtin_amdgcn_mfma_f32_16x16x32_bf16(
                        af[m], bfr[n], acc[m][n], 0, 0, 0);
        }
        __syncthreads();
    }

#pragma unroll
    for (int m = 0; m < FM; m++) {
        int rbase = blockIdx.y*BM + wr*(BM/WM) + m*16 + l4*4;
#pragma unroll
        for (int n = 0; n < FN; n++) {
            int col = blockIdx.x*BN + wc*(BN/WN) + n*16 + l15;
#pragma unroll
            for (int r = 0; r < 4; r++) {
                int row = rbase + r;
                float v = acc[m][n][r];
                if (EPI & ESCALE) v *= scale;
                if (EPI & EBIAS)  v += bias[col];
                if (EPI & ERELU)  v = fmaxf(v, 0.f);
                if (EPI & ERES)   v += res[(long)row * N + col];
                long idx;
                if (OL == OL_PLAIN)
                    idx = (long)row * N + col;
                else if (OL == OL_QKV)
                    idx = ((long)((row >> 10) * HH + (col >> 6))) * 65536
                          + (long)(row & 1023) * 64 + (col & 63);
                else // OL_VT -> [B,H,HS,T]
                    idx = ((long)((row >> 10) * HH + (col >> 6))) * 65536
                          + (long)(col & 63) * 1024 + (row & 1023);
                stv(&C[(long)bh * sC + idx], v);
            }
        }
    }
}

// ---------------- Fused attention: QK^T -> softmax -> wei + PV ---------------
// grid (8 q-tiles, 64 bh), 256 thr = 4 waves (2x2). Q-tile 128 rows.
// Pass 1: online row max/sum. Pass 2: recompute S, write normalized P to wei,
// accumulate O = P@V, write attn (headcat bf16).
__global__ __launch_bounds__(256, 2)
void fattn_k(const ushort* __restrict__ q_, const ushort* __restrict__ k_,
             const ushort* __restrict__ vt, float* __restrict__ wei,
             ushort* __restrict__ attn)
{
    __shared__ ushort Qs[128*64];
    __shared__ ushort Ks[128*64];
    __shared__ ushort Vs[64*128];
    __shared__ ushort Ps[128*128];          // pass2; pass1 reuses as smax/ssum
    float* smax = (float*)Ps;               // [2][128]
    float* ssum = smax + 256;               // [2][128]

    const int tid = threadIdx.x;
    const int w = tid >> 6, l = tid & 63;
    const int wr = w >> 1, wc = w & 1;
    const int l15 = l & 15, l4 = l >> 4;
    const int bh = blockIdx.y;
    const int q0 = blockIdx.x * 128;
    const int arow = tid >> 3, achk = tid & 7;

    const ushort* Qp = q_ + (long)bh * 65536;
    const ushort* Kp = k_ + (long)bh * 65536;
    const ushort* Vp = vt + (long)bh * 65536;

    // stage Q (persistent)
#pragma unroll
    for (int i = 0; i < 4; i++)
        gload16(Qp + (long)(q0 + i*32 + arow) * 64 + achk*8, &Qs[(i*32 + w*8)*64]);

    float m_run[4][4], l_run[4][4];
#pragma unroll
    for (int m = 0; m < 4; m++)
#pragma unroll
        for (int r = 0; r < 4; r++) { m_run[m][r] = -1e30f; l_run[m][r] = 0.f; }

    // ---- pass 1: stats ----
    for (int st = 0; st < 8; ++st) {
#pragma unroll
        for (int i = 0; i < 4; i++)
            gload16(Kp + (long)(st*128 + i*32 + arow) * 64 + achk*8,
                    &Ks[(i*32 + w*8)*64]);
        __syncthreads();

        f32x4 sacc[4][4];
#pragma unroll
        for (int m = 0; m < 4; m++)
#pragma unroll
            for (int n = 0; n < 4; n++) sacc[m][n] = (f32x4){0.f,0.f,0.f,0.f};
#pragma unroll
        for (int kk = 0; kk < 2; kk++) {
            const int ko = kk*32 + l4*8;
            bf16x8 af[4], bfr[4];
#pragma unroll
            for (int m = 0; m < 4; m++)
                af[m] = *(const bf16x8*)&Qs[(wr*64 + m*16 + l15)*64 + ko];
#pragma unroll
            for (int n = 0; n < 4; n++)
                bfr[n] = *(const bf16x8*)&Ks[(wc*64 + n*16 + l15)*64 + ko];
#pragma unroll
            for (int m = 0; m < 4; m++)
#pragma unroll
                for (int n = 0; n < 4; n++)
                    sacc[m][n] = __builtin_amdgcn_mfma_f32_16x16x32_bf16(
                        af[m], bfr[n], sacc[m][n], 0, 0, 0);
        }

        float tma[4][4], tsa[4][4];
#pragma unroll
        for (int m = 0; m < 4; m++)
#pragma unroll
            for (int r = 0; r < 4; r++) {
                float ma = -1e30f;
#pragma unroll
                for (int n = 0; n < 4; n++) {
                    sacc[m][n][r] *= 0.125f;
                    ma = fmaxf(ma, sacc[m][n][r]);
                }
#pragma unroll
                for (int d = 1; d < 16; d <<= 1) ma = fmaxf(ma, __shfl_xor(ma, d));
                float sa = 0.f;
#pragma unroll
                for (int n = 0; n < 4; n++) sa += __expf(sacc[m][n][r] - ma);
#pragma unroll
                for (int d = 1; d < 16; d <<= 1) sa += __shfl_xor(sa, d);
                tma[m][r] = ma; tsa[m][r] = sa;
                if (l15 == 0) {
                    int rg = wr*64 + m*16 + l4*4 + r;
                    smax[wc*128 + rg] = ma;
                    ssum[wc*128 + rg] = sa;
                }
            }
        __syncthreads();
#pragma unroll
        for (int m = 0; m < 4; m++)
#pragma unroll
            for (int r = 0; r < 4; r++) {
                int rg = wr*64 + m*16 + l4*4 + r;
                float mo = smax[(wc^1)*128 + rg], so = ssum[(wc^1)*128 + rg];
                float ma = tma[m][r], sa = tsa[m][r];
                float mt = fmaxf(ma, mo);
                float stt = sa*__expf(ma - mt) + so*__expf(mo - mt);
                float mn = fmaxf(m_run[m][r], mt);
                l_run[m][r] = l_run[m][r]*__expf(m_run[m][r] - mn) + stt*__expf(mt - mn);
                m_run[m][r] = mn;
            }
        __syncthreads();   // protect smax/ssum & Ks before next iteration
    }

    float linv[4][4];
#pragma unroll
    for (int m = 0; m < 4; m++)
#pragma unroll
        for (int r = 0; r < 4; r++) linv[m][r] = 1.0f / l_run[m][r];

    // ---- pass 2: P + PV ----
    f32x4 oacc[4][2];
#pragma unroll
    for (int m = 0; m < 4; m++)
#pragma unroll
        for (int n = 0; n < 2; n++) oacc[m][n] = (f32x4){0.f,0.f,0.f,0.f};

    for (int st = 0; st < 8; ++st) {
#pragma unroll
        for (int i = 0; i < 4; i++)
            gload16(Kp + (long)(st*128 + i*32 + arow) * 64 + achk*8,
                    &Ks[(i*32 + w*8)*64]);
#pragma unroll
        for (int i = 0; i < 4; i++)
            gload16(Vp + (long)(i*16 + (tid>>4)) * 1024 + st*128 + (tid&15)*8,
                    &Vs[(i*16 + w*4)*128]);
        __syncthreads();

        f32x4 sacc[4][4];
#pragma unroll
        for (int m = 0; m < 4; m++)
#pragma unroll
            for (int n = 0; n < 4; n++) sacc[m][n] = (f32x4){0.f,0.f,0.f,0.f};
#pragma unroll
        for (int kk = 0; kk < 2; kk++) {
            const int ko = kk*32 + l4*8;
            bf16x8 af[4], bfr[4];
#pragma unroll
            for (int m = 0; m < 4; m++)
                af[m] = *(const bf16x8*)&Qs[(wr*64 + m*16 + l15)*64 + ko];
#pragma unroll
            for (int n = 0; n < 4; n++)
                bfr[n] = *(const bf16x8*)&Ks[(wc*64 + n*16 + l15)*64 + ko];
#pragma unroll
            for (int m = 0; m < 4; m++)
#pragma unroll
                for (int n = 0; n < 4; n++)
                    sacc[m][n] = __builtin_amdgcn_mfma_f32_16x16x32_bf16(
                        af[m], bfr[n], sacc[m][n], 0, 0, 0);
        }

        float* wrow = wei + (long)bh * (TT*(long)TT) + st*128;
#pragma unroll
        for (int m = 0; m < 4; m++)
#pragma unroll
            for (int r = 0; r < 4; r++) {
                int rg = wr*64 + m*16 + l4*4 + r;
                float mm = m_run[m][r], li = linv[m][r];
#pragma unroll
                for (int n = 0; n < 4; n++) {
                    int col = wc*64 + n*16 + l15;
                    float pu = __expf(sacc[m][n][r]*0.125f - mm);
                    wrow[(long)(q0 + rg) * TT + col] = pu * li;
                    Ps[rg*128 + col] = f2b(pu);
                }
            }
        __syncthreads();

        // PV: O += P @ V   (K = 128 over 4 chunks)
#pragma unroll
        for (int kc = 0; kc < 4; ++kc) {
            const int ko = kc*32 + l4*8;
            bf16x8 pa[4], vb[2];
#pragma unroll
            for (int m = 0; m < 4; m++)
                pa[m] = *(const bf16x8*)&Ps[(wr*64 + m*16 + l15)*128 + ko];
#pragma unroll
            for (int n = 0; n < 2; n++)
                vb[n] = *(const bf16x8*)&Vs[(wc*32 + n*16 + l15)*128 + ko];
#pragma unroll
            for (int m = 0; m < 4; m++)
#pragma unroll
                for (int n = 0; n < 2; n++)
                    oacc[m][n] = __builtin_amdgcn_mfma_f32_16x16x32_bf16(
                        pa[m], vb[n], oacc[m][n], 0, 0, 0);
        }
        __syncthreads();
    }

    // epilogue: attn [B,T,C] bf16, col = h*64 + wc*32 + n*16 + l15
#pragma unroll
    for (int m = 0; m < 4; m++)
#pragma unroll
        for (int r = 0; r < 4; r++) {
            int rg = wr*64 + m*16 + l4*4 + r;
            long rowbase = ((long)(bh >> 4) * TT + q0 + rg) * CC + (long)(bh & 15) * HSZ;
#pragma unroll
            for (int n = 0; n < 2; n++)
                attn[rowbase + wc*32 + n*16 + l15] = f2b(oacc[m][n][r] * linv[m][r]);
        }
}

// ---------------- launch -----------------------------------------------------
extern "C" void kernel_launch(void* const* d_in, const int* in_sizes, int n_in,
                              void* d_out, int out_size, void* d_ws, size_t ws_size,
                              hipStream_t stream)
{
    const float* x      = (const float*)d_in[0];
    const float* wq     = (const float*)d_in[1];
    const float* wk     = (const float*)d_in[2];
    const float* wv     = (const float*)d_in[3];
    const float* w_proj = (const float*)d_in[4];
    const float* b_proj = (const float*)d_in[5];
    const float* w1     = (const float*)d_in[6];
    const float* b1     = (const float*)d_in[7];
    const float* w2     = (const float*)d_in[8];
    const float* b2     = (const float*)d_in[9];
    const float* g1     = (const float*)d_in[10];
    const float* be1    = (const float*)d_in[11];
    const float* g2     = (const float*)d_in[12];
    const float* be2    = (const float*)d_in[13];

    float* out_x = (float*)d_out;                  // [B,T,C]
    float* wei   = out_x + (long)NTOK * CC;        // [B,H,T,T] f32

    const long MEL = 1 << 20;
    ushort* ws16 = (ushort*)d_ws;
    ushort* h    = ws16;                 // [4096,1024] bf16 (LN1 out)
    ushort* q_   = ws16 + 4*MEL;         // [B,H,T,HS]
    ushort* k_   = ws16 + 8*MEL;         // [B,H,T,HS]
    ushort* vt   = ws16 + 12*MEL;        // [B,H,HS,T]
    ushort* attn = ws16 + 16*MEL;        // [4096,1024] bf16
    ushort* h2   = ws16 + 20*MEL;        // [4096,1024] bf16 (LN2 out)
    ushort* a1   = ws16 + 24*MEL;        // [4096,4096] bf16
    ushort* wqt  = ws16 + 40*MEL;        // [1024,1024] bf16 (B^T)
    ushort* wkt  = ws16 + 41*MEL;
    ushort* wvt  = ws16 + 42*MEL;
    ushort* wpT  = ws16 + 43*MEL;
    ushort* w1T  = ws16 + 44*MEL;        // [4096,1024]
    ushort* w2T  = ws16 + 48*MEL;        // [1024,4096]
    float*  x1   = (float*)(ws16 + 52*MEL);  // [4096,1024] f32

    tcvt_k<<<dim3(2, 32, 16),  256, 0, stream>>>(wq,     wqt, 1024, 64);
    tcvt_k<<<dim3(2, 32, 16),  256, 0, stream>>>(wk,     wkt, 1024, 64);
    tcvt_k<<<dim3(2, 32, 16),  256, 0, stream>>>(wv,     wvt, 1024, 64);
    tcvt_k<<<dim3(32, 32, 1),  256, 0, stream>>>(w_proj, wpT, 1024, 1024);
    tcvt_k<<<dim3(128, 32, 1), 256, 0, stream>>>(w1,     w1T, 1024, 4096);
    tcvt_k<<<dim3(32, 128, 1), 256, 0, stream>>>(w2,     w2T, 4096, 1024);

    // 1. h = LN(x)
    ln_k<<<NTOK, 256, 0, stream>>>(x, g1, be1, h);

    // 2. q,k,v projections
    mgemm_k<128,128,2,2,OL_QKV,0,ushort><<<dim3(8,32,1), 256, 0, stream>>>(
        h, wqt, nullptr, nullptr, q_, NTOK, CC, CC, 0,0,0, 0.f);
    mgemm_k<128,128,2,2,OL_QKV,0,ushort><<<dim3(8,32,1), 256, 0, stream>>>(
        h, wkt, nullptr, nullptr, k_, NTOK, CC, CC, 0,0,0, 0.f);
    mgemm_k<128,128,2,2,OL_VT,0,ushort><<<dim3(8,32,1), 256, 0, stream>>>(
        h, wvt, nullptr, nullptr, vt, NTOK, CC, CC, 0,0,0, 0.f);

    // 3-5. fused attention: wei (f32, d_out) + attn (bf16 headcat)
    fattn_k<<<dim3(8, 64), 256, 0, stream>>>(q_, k_, vt, wei, attn);

    // 6. x1 = x + attn @ w_proj + b_proj  (f32)
    mgemm_k<128,128,2,2,OL_PLAIN,EBIAS|ERES,float><<<dim3(8,32,1), 256, 0, stream>>>(
        attn, wpT, b_proj, x, x1, NTOK, CC, CC, 0,0,0, 0.f);

    // 7. h2 = LN(x1)
    ln_k<<<NTOK, 256, 0, stream>>>(x1, g2, be2, h2);

    // 8. a1 = relu(h2 @ w1 + b1)  bf16
    mgemm_k<128,128,2,2,OL_PLAIN,EBIAS|ERELU,ushort><<<dim3(32,32,1), 256, 0, stream>>>(
        h2, w1T, b1, nullptr, a1, NTOK, DFF, CC, 0,0,0, 0.f);

    // 9. out = x1 + a1 @ w2 + b2  (f32)
    mgemm_k<128,128,2,2,OL_PLAIN,EBIAS|ERES,float><<<dim3(8,32,1), 256, 0, stream>>>(
        a1, w2T, b2, x1, out_x, NTOK, CC, DFF, 0,0,0, 0.f);
}

// Round 4
// 393.708 us; speedup vs baseline: 8.3777x; 1.1755x over previous
//
#include <hip/hip_runtime.h>
#include <hip/hip_bf16.h>

// Problem constants
#define BB    4
#define TT    1024
#define CC    1024
#define HH    16
#define HSZ   64
#define DFF   4096
#define NTOK  (BB*TT)          // 4096
#define BHN   (BB*HH)          // 64

typedef __attribute__((ext_vector_type(8))) short bf16x8;
typedef __attribute__((ext_vector_type(4))) float f32x4;

__device__ __forceinline__ ushort f2b(float v) {
    union { float f; unsigned u; } c; c.f = v;
    unsigned r = c.u + 0x7fffu + ((c.u >> 16) & 1u);   // RNE
    return (ushort)(r >> 16);
}
__device__ __forceinline__ void stv(float* p, float v)  { *p = v; }
__device__ __forceinline__ void stv(ushort* p, float v) { *p = f2b(v); }

__device__ __forceinline__ void gload16(const void* g, void* l) {
    __builtin_amdgcn_global_load_lds(
        (const __attribute__((address_space(1))) void*)g,
        (__attribute__((address_space(3))) void*)l, 16, 0, 0);
}

// ---------------- LayerNorm: f32 in -> bf16 out ------------------------------
__global__ __launch_bounds__(256)
void ln_k(const float* __restrict__ x, const float* __restrict__ g,
          const float* __restrict__ be, ushort* __restrict__ o)
{
    __shared__ float s1[4], s2[4];
    long row = blockIdx.x;
    const float4* xr = (const float4*)(x + row * CC);
    float4 v = xr[threadIdx.x];
    float a = v.x + v.y + v.z + v.w;
    float b = v.x*v.x + v.y*v.y + v.z*v.z + v.w*v.w;
    for (int off = 32; off > 0; off >>= 1) {
        a += __shfl_down(a, off);
        b += __shfl_down(b, off);
    }
    if ((threadIdx.x & 63) == 0) { s1[threadIdx.x >> 6] = a; s2[threadIdx.x >> 6] = b; }
    __syncthreads();
    float sum = s1[0] + s1[1] + s1[2] + s1[3];
    float sq  = s2[0] + s2[1] + s2[2] + s2[3];
    float mu  = sum * (1.0f / CC);
    float var = sq * (1.0f / CC) - mu * mu;
    float inv = rsqrtf(var + 1e-5f);
    float4 gg = ((const float4*)g)[threadIdx.x];
    float4 bb = ((const float4*)be)[threadIdx.x];
    ushort4 r;
    r.x = f2b((v.x - mu) * inv * gg.x + bb.x);
    r.y = f2b((v.y - mu) * inv * gg.y + bb.y);
    r.z = f2b((v.z - mu) * inv * gg.z + bb.z);
    r.w = f2b((v.w - mu) * inv * gg.w + bb.w);
    ((ushort4*)(o + row * CC))[threadIdx.x] = r;
}

// ---------------- Transposed f32 -> bf16 convert (weights) -------------------
__global__ __launch_bounds__(256)
void tcvt_k(const float* __restrict__ src, ushort* __restrict__ dst, int R, int Cc)
{
    __shared__ float t[32][33];
    const long bz = blockIdx.z;
    src += bz * (long)R * Cc;
    dst += bz * (long)R * Cc;
    int r0 = blockIdx.y * 32, c0 = blockIdx.x * 32;
    int tx = threadIdx.x & 31, ty = threadIdx.x >> 5;
#pragma unroll
    for (int i = 0; i < 4; i++)
        t[ty + 8*i][tx] = src[(long)(r0 + ty + 8*i) * Cc + c0 + tx];
    __syncthreads();
#pragma unroll
    for (int i = 0; i < 4; i++)
        dst[(long)(c0 + ty + 8*i) * R + r0 + tx] = f2b(t[tx][ty + 8*i]);
}

// ---------------- bf16 MFMA GEMM ---------------------------------------------
enum { OL_PLAIN = 0, OL_QKV3 = 1 };
constexpr int EBIAS = 1, ERELU = 2, ERES = 4, ESCALE = 8;

template<int BM, int BN, int WM, int WN, int OL, int EPI, typename OutT>
__global__ __launch_bounds__(256)
void mgemm_k(const ushort* __restrict__ A, const ushort* __restrict__ Bt,
             const float* __restrict__ bias, const float* __restrict__ res,
             OutT* __restrict__ C, int M, int N, int K,
             long sA, long sB, long sC, float scale)
{
    constexpr int BK = 64;
    constexpr int FM = BM / WM / 16, FN = BN / WN / 16;
    __shared__ ushort As[BM * BK];
    __shared__ ushort Bs[BN * BK];
    const int tid = threadIdx.x;
    const int w = tid >> 6, l = tid & 63;
    const int wr = w / WN, wc = w % WN;
    const int l15 = l & 15, l4 = l >> 4;
    const int bh = blockIdx.z;
    const ushort* Ap = A  + (long)bh * sA + (long)(blockIdx.y * BM) * K;
    const ushort* Bp = Bt + (long)bh * sB + (long)(blockIdx.x * BN) * K;

    f32x4 acc[FM][FN];
#pragma unroll
    for (int m = 0; m < FM; m++)
#pragma unroll
        for (int n = 0; n < FN; n++) acc[m][n] = (f32x4){0.f, 0.f, 0.f, 0.f};

    const int arow = tid >> 3;
    const int achk = tid & 7;

    for (int k0 = 0; k0 < K; k0 += BK) {
#pragma unroll
        for (int i = 0; i < BM / 32; i++)
            gload16(Ap + (long)(i*32 + arow) * K + k0 + achk*8,
                    &As[(i*32 + w*8) * BK]);
#pragma unroll
        for (int i = 0; i < BN / 32; i++)
            gload16(Bp + (long)(i*32 + arow) * K + k0 + achk*8,
                    &Bs[(i*32 + w*8) * BK]);
        __syncthreads();
#pragma unroll
        for (int kk = 0; kk < 2; kk++) {
            const int ko = kk*32 + l4*8;
            bf16x8 af[FM], bfr[FN];
#pragma unroll
            for (int m = 0; m < FM; m++)
                af[m] = *(const bf16x8*)&As[(wr*(BM/WM) + m*16 + l15) * BK + ko];
#pragma unroll
            for (int n = 0; n < FN; n++)
                bfr[n] = *(const bf16x8*)&Bs[(wc*(BN/WN) + n*16 + l15) * BK + ko];
#pragma unroll
            for (int m = 0; m < FM; m++)
#pragma unroll
                for (int n = 0; n < FN; n++)
                    acc[m][n] = __builtin_amdgcn_mfma_f32_16x16x32_bf16(
                        af[m], bfr[n], acc[m][n], 0, 0, 0);
        }
        __syncthreads();
    }

#pragma unroll
    for (int m = 0; m < FM; m++) {
        int rbase = blockIdx.y*BM + wr*(BM/WM) + m*16 + l4*4;
#pragma unroll
        for (int n = 0; n < FN; n++) {
            int col = blockIdx.x*BN + wc*(BN/WN) + n*16 + l15;
#pragma unroll
            for (int r = 0; r < 4; r++) {
                int row = rbase + r;
                float v = acc[m][n][r];
                if (EPI & ESCALE) v *= scale;
                if (EPI & EBIAS)  v += bias[col];
                if (EPI & ERELU)  v = fmaxf(v, 0.f);
                if (EPI & ERES)   v += res[(long)row * N + col];
                long idx;
                if (OL == OL_PLAIN) {
                    idx = (long)row * N + col;
                } else {
                    // fused QKV: col segment 0=q,1=k,2=v(transposed)
                    int seg = col >> 10;
                    int cl  = col & 1023;
                    long bh_ = ((long)((row >> 10) * HH + (cl >> 6))) * 65536;
                    long off = (seg == 2)
                        ? bh_ + (long)(cl & 63) * 1024 + (row & 1023)
                        : bh_ + (long)(row & 1023) * 64 + (cl & 63);
                    idx = (long)seg * (4L << 20) + off;
                }
                stv(&C[(long)bh * sC + idx], v);
            }
        }
    }
}

// ---------------- Fused attention (no-max softmax: shift-invariant) ----------
// Pass 1: row sums of exp(S). Pass 2: recompute S, write normalized P to wei
// (non-temporal), PV with normalized bf16 P.
__global__ __launch_bounds__(256, 2)
void fattn_k(const ushort* __restrict__ q_, const ushort* __restrict__ k_,
             const ushort* __restrict__ vt, float* __restrict__ wei,
             ushort* __restrict__ attn)
{
    __shared__ ushort Qs[128*64];
    __shared__ ushort Ks[128*64];
    __shared__ ushort Vs[64*128];
    __shared__ ushort Ps[128*128];          // pass2 P tile; pass1-end reduce scratch
    float* sred = (float*)Ps;               // [2][128]

    const int tid = threadIdx.x;
    const int w = tid >> 6, l = tid & 63;
    const int wr = w >> 1, wc = w & 1;
    const int l15 = l & 15, l4 = l >> 4;
    const int bh = blockIdx.y;
    const int q0 = blockIdx.x * 128;
    const int arow = tid >> 3, achk = tid & 7;

    const ushort* Qp = q_ + (long)bh * 65536;
    const ushort* Kp = k_ + (long)bh * 65536;
    const ushort* Vp = vt + (long)bh * 65536;

    // stage Q (persistent)
#pragma unroll
    for (int i = 0; i < 4; i++)
        gload16(Qp + (long)(q0 + i*32 + arow) * 64 + achk*8, &Qs[(i*32 + w*8)*64]);

    float ssum[4][4];
#pragma unroll
    for (int m = 0; m < 4; m++)
#pragma unroll
        for (int r = 0; r < 4; r++) ssum[m][r] = 0.f;

    // ---- pass 1: row sums of exp(S) ----
    for (int st = 0; st < 8; ++st) {
#pragma unroll
        for (int i = 0; i < 4; i++)
            gload16(Kp + (long)(st*128 + i*32 + arow) * 64 + achk*8,
                    &Ks[(i*32 + w*8)*64]);
        __syncthreads();

        f32x4 sacc[4][4];
#pragma unroll
        for (int m = 0; m < 4; m++)
#pragma unroll
            for (int n = 0; n < 4; n++) sacc[m][n] = (f32x4){0.f,0.f,0.f,0.f};
#pragma unroll
        for (int kk = 0; kk < 2; kk++) {
            const int ko = kk*32 + l4*8;
            bf16x8 af[4], bfr[4];
#pragma unroll
            for (int m = 0; m < 4; m++)
                af[m] = *(const bf16x8*)&Qs[(wr*64 + m*16 + l15)*64 + ko];
#pragma unroll
            for (int n = 0; n < 4; n++)
                bfr[n] = *(const bf16x8*)&Ks[(wc*64 + n*16 + l15)*64 + ko];
#pragma unroll
            for (int m = 0; m < 4; m++)
#pragma unroll
                for (int n = 0; n < 4; n++)
                    sacc[m][n] = __builtin_amdgcn_mfma_f32_16x16x32_bf16(
                        af[m], bfr[n], sacc[m][n], 0, 0, 0);
        }
#pragma unroll
        for (int m = 0; m < 4; m++)
#pragma unroll
            for (int r = 0; r < 4; r++) {
                float s = 0.f;
#pragma unroll
                for (int n = 0; n < 4; n++) s += __expf(sacc[m][n][r] * 0.125f);
                ssum[m][r] += s;
            }
        __syncthreads();   // Ks consumed before next stage
    }

    // final reduce: 16 lanes, then across wc via LDS
    float linv[4][4];
#pragma unroll
    for (int m = 0; m < 4; m++)
#pragma unroll
        for (int r = 0; r < 4; r++) {
            float s = ssum[m][r];
#pragma unroll
            for (int d = 1; d < 16; d <<= 1) s += __shfl_xor(s, d);
            ssum[m][r] = s;
            if (l15 == 0) sred[wc*128 + wr*64 + m*16 + l4*4 + r] = s;
        }
    __syncthreads();
#pragma unroll
    for (int m = 0; m < 4; m++)
#pragma unroll
        for (int r = 0; r < 4; r++) {
            int rg = wr*64 + m*16 + l4*4 + r;
            linv[m][r] = 1.0f / (sred[rg] + sred[128 + rg]);
        }

    // ---- pass 2: P + PV ----
    f32x4 oacc[4][2];
#pragma unroll
    for (int m = 0; m < 4; m++)
#pragma unroll
        for (int n = 0; n < 2; n++) oacc[m][n] = (f32x4){0.f,0.f,0.f,0.f};

    for (int st = 0; st < 8; ++st) {
#pragma unroll
        for (int i = 0; i < 4; i++)
            gload16(Kp + (long)(st*128 + i*32 + arow) * 64 + achk*8,
                    &Ks[(i*32 + w*8)*64]);
#pragma unroll
        for (int i = 0; i < 4; i++)
            gload16(Vp + (long)(i*16 + (tid>>4)) * 1024 + st*128 + (tid&15)*8,
                    &Vs[(i*16 + w*4)*128]);
        __syncthreads();

        f32x4 sacc[4][4];
#pragma unroll
        for (int m = 0; m < 4; m++)
#pragma unroll
            for (int n = 0; n < 4; n++) sacc[m][n] = (f32x4){0.f,0.f,0.f,0.f};
#pragma unroll
        for (int kk = 0; kk < 2; kk++) {
            const int ko = kk*32 + l4*8;
            bf16x8 af[4], bfr[4];
#pragma unroll
            for (int m = 0; m < 4; m++)
                af[m] = *(const bf16x8*)&Qs[(wr*64 + m*16 + l15)*64 + ko];
#pragma unroll
            for (int n = 0; n < 4; n++)
                bfr[n] = *(const bf16x8*)&Ks[(wc*64 + n*16 + l15)*64 + ko];
#pragma unroll
            for (int m = 0; m < 4; m++)
#pragma unroll
                for (int n = 0; n < 4; n++)
                    sacc[m][n] = __builtin_amdgcn_mfma_f32_16x16x32_bf16(
                        af[m], bfr[n], sacc[m][n], 0, 0, 0);
        }

        float* wrow = wei + (long)bh * (TT*(long)TT) + st*128;
#pragma unroll
        for (int m = 0; m < 4; m++)
#pragma unroll
            for (int r = 0; r < 4; r++) {
                int rg = wr*64 + m*16 + l4*4 + r;
                float li = linv[m][r];
#pragma unroll
                for (int n = 0; n < 4; n++) {
                    int col = wc*64 + n*16 + l15;
                    float p = __expf(sacc[m][n][r] * 0.125f) * li;
                    __builtin_nontemporal_store(p, &wrow[(long)(q0 + rg) * TT + col]);
                    Ps[rg*128 + col] = f2b(p);
                }
            }
        __syncthreads();

        // PV: O += P @ V (normalized P)
#pragma unroll
        for (int kc = 0; kc < 4; ++kc) {
            const int ko = kc*32 + l4*8;
            bf16x8 pa[4], vb[2];
#pragma unroll
            for (int m = 0; m < 4; m++)
                pa[m] = *(const bf16x8*)&Ps[(wr*64 + m*16 + l15)*128 + ko];
#pragma unroll
            for (int n = 0; n < 2; n++)
                vb[n] = *(const bf16x8*)&Vs[(wc*32 + n*16 + l15)*128 + ko];
#pragma unroll
            for (int m = 0; m < 4; m++)
#pragma unroll
                for (int n = 0; n < 2; n++)
                    oacc[m][n] = __builtin_amdgcn_mfma_f32_16x16x32_bf16(
                        pa[m], vb[n], oacc[m][n], 0, 0, 0);
        }
        __syncthreads();
    }

    // epilogue: attn [B,T,C] bf16
#pragma unroll
    for (int m = 0; m < 4; m++)
#pragma unroll
        for (int r = 0; r < 4; r++) {
            int rg = wr*64 + m*16 + l4*4 + r;
            long rowbase = ((long)(bh >> 4) * TT + q0 + rg) * CC + (long)(bh & 15) * HSZ;
#pragma unroll
            for (int n = 0; n < 2; n++)
                attn[rowbase + wc*32 + n*16 + l15] = f2b(oacc[m][n][r]);
        }
}

// ---------------- launch -----------------------------------------------------
extern "C" void kernel_launch(void* const* d_in, const int* in_sizes, int n_in,
                              void* d_out, int out_size, void* d_ws, size_t ws_size,
                              hipStream_t stream)
{
    const float* x      = (const float*)d_in[0];
    const float* wq     = (const float*)d_in[1];
    const float* wk     = (const float*)d_in[2];
    const float* wv     = (const float*)d_in[3];
    const float* w_proj = (const float*)d_in[4];
    const float* b_proj = (const float*)d_in[5];
    const float* w1     = (const float*)d_in[6];
    const float* b1     = (const float*)d_in[7];
    const float* w2     = (const float*)d_in[8];
    const float* b2     = (const float*)d_in[9];
    const float* g1     = (const float*)d_in[10];
    const float* be1    = (const float*)d_in[11];
    const float* g2     = (const float*)d_in[12];
    const float* be2    = (const float*)d_in[13];

    float* out_x = (float*)d_out;                  // [B,T,C]
    float* wei   = out_x + (long)NTOK * CC;        // [B,H,T,T] f32

    const long MEL = 1 << 20;
    ushort* ws16 = (ushort*)d_ws;
    ushort* h    = ws16;                 // [4096,1024] bf16 (LN1 out)
    ushort* q_   = ws16 + 4*MEL;         // [B,H,T,HS]   (k_ = q_+4M, vt = q_+8M)
    ushort* k_   = ws16 + 8*MEL;
    ushort* vt   = ws16 + 12*MEL;        // [B,H,HS,T]
    ushort* attn = ws16 + 16*MEL;        // [4096,1024] bf16
    ushort* h2   = ws16 + 20*MEL;        // [4096,1024] bf16 (LN2 out)
    ushort* a1   = ws16 + 24*MEL;        // [4096,4096] bf16
    ushort* wqkvT= ws16 + 40*MEL;        // [3072,1024] bf16 (q rows 0-1023, k, v)
    ushort* w1T  = ws16 + 44*MEL;        // [4096,1024]
    ushort* wpT  = ws16 + 48*MEL;        // [1024,1024]
    ushort* w2T  = ws16 + 49*MEL;        // [1024,4096]
    float*  x1   = (float*)(ws16 + 54*MEL);  // [4096,1024] f32

    // weight conversions (transposed bf16); wq/wk/wv -> contiguous wqkvT
    tcvt_k<<<dim3(2, 32, 16),  256, 0, stream>>>(wq,     wqkvT,           1024, 64);
    tcvt_k<<<dim3(2, 32, 16),  256, 0, stream>>>(wk,     wqkvT + 1*MEL,   1024, 64);
    tcvt_k<<<dim3(2, 32, 16),  256, 0, stream>>>(wv,     wqkvT + 2*MEL,   1024, 64);
    tcvt_k<<<dim3(32, 32, 1),  256, 0, stream>>>(w_proj, wpT, 1024, 1024);
    tcvt_k<<<dim3(128, 32, 1), 256, 0, stream>>>(w1,     w1T, 1024, 4096);
    tcvt_k<<<dim3(32, 128, 1), 256, 0, stream>>>(w2,     w2T, 4096, 1024);

    // 1. h = LN(x)
    ln_k<<<NTOK, 256, 0, stream>>>(x, g1, be1, h);

    // 2. fused q,k,v projection (N=3072)
    mgemm_k<128,128,2,2,OL_QKV3,0,ushort><<<dim3(24,32,1), 256, 0, stream>>>(
        h, wqkvT, nullptr, nullptr, q_, NTOK, 3072, CC, 0,0,0, 0.f);

    // 3-5. fused attention: wei (f32, d_out) + attn (bf16 headcat)
    fattn_k<<<dim3(8, 64), 256, 0, stream>>>(q_, k_, vt, wei, attn);

    // 6. x1 = x + attn @ w_proj + b_proj  (f32)
    mgemm_k<128,128,2,2,OL_PLAIN,EBIAS|ERES,float><<<dim3(8,32,1), 256, 0, stream>>>(
        attn, wpT, b_proj, x, x1, NTOK, CC, CC, 0,0,0, 0.f);

    // 7. h2 = LN(x1)
    ln_k<<<NTOK, 256, 0, stream>>>(x1, g2, be2, h2);

    // 8. a1 = relu(h2 @ w1 + b1)  bf16
    mgemm_k<128,128,2,2,OL_PLAIN,EBIAS|ERELU,ushort><<<dim3(32,32,1), 256, 0, stream>>>(
        h2, w1T, b1, nullptr, a1, NTOK, DFF, CC, 0,0,0, 0.f);

    // 9. out = x1 + a1 @ w2 + b2  (f32)
    mgemm_k<128,128,2,2,OL_PLAIN,EBIAS|ERES,float><<<dim3(8,32,1), 256, 0, stream>>>(
        a1, w2T, b2, x1, out_x, NTOK, CC, DFF, 0,0,0, 0.f);
}

// Round 5
// 381.282 us; speedup vs baseline: 8.6508x; 1.0326x over previous
//
#include <hip/hip_runtime.h>
#include <hip/hip_bf16.h>

// Problem constants
#define BB    4
#define TT    1024
#define CC    1024
#define HH    16
#define HSZ   64
#define DFF   4096
#define NTOK  (BB*TT)          // 4096
#define BHN   (BB*HH)          // 64

typedef __attribute__((ext_vector_type(8))) short bf16x8;
typedef __attribute__((ext_vector_type(4))) float f32x4;

__device__ __forceinline__ ushort f2b(float v) {
    union { float f; unsigned u; } c; c.f = v;
    unsigned r = c.u + 0x7fffu + ((c.u >> 16) & 1u);   // RNE
    return (ushort)(r >> 16);
}
__device__ __forceinline__ void stv(float* p, float v)  { *p = v; }
__device__ __forceinline__ void stv(ushort* p, float v) { *p = f2b(v); }

__device__ __forceinline__ void gload16(const void* g, void* l) {
    __builtin_amdgcn_global_load_lds(
        (const __attribute__((address_space(1))) void*)g,
        (__attribute__((address_space(3))) void*)l, 16, 0, 0);
}

// ---------------- LayerNorm: f32 in -> bf16 out ------------------------------
__global__ __launch_bounds__(256)
void ln_k(const float* __restrict__ x, const float* __restrict__ g,
          const float* __restrict__ be, ushort* __restrict__ o)
{
    __shared__ float s1[4], s2[4];
    long row = blockIdx.x;
    const float4* xr = (const float4*)(x + row * CC);
    float4 v = xr[threadIdx.x];
    float a = v.x + v.y + v.z + v.w;
    float b = v.x*v.x + v.y*v.y + v.z*v.z + v.w*v.w;
    for (int off = 32; off > 0; off >>= 1) {
        a += __shfl_down(a, off);
        b += __shfl_down(b, off);
    }
    if ((threadIdx.x & 63) == 0) { s1[threadIdx.x >> 6] = a; s2[threadIdx.x >> 6] = b; }
    __syncthreads();
    float sum = s1[0] + s1[1] + s1[2] + s1[3];
    float sq  = s2[0] + s2[1] + s2[2] + s2[3];
    float mu  = sum * (1.0f / CC);
    float var = sq * (1.0f / CC) - mu * mu;
    float inv = rsqrtf(var + 1e-5f);
    float4 gg = ((const float4*)g)[threadIdx.x];
    float4 bb = ((const float4*)be)[threadIdx.x];
    ushort4 r;
    r.x = f2b((v.x - mu) * inv * gg.x + bb.x);
    r.y = f2b((v.y - mu) * inv * gg.y + bb.y);
    r.z = f2b((v.z - mu) * inv * gg.z + bb.z);
    r.w = f2b((v.w - mu) * inv * gg.w + bb.w);
    ((ushort4*)(o + row * CC))[threadIdx.x] = r;
}

// ---------------- All weight conversions (transposed f32->bf16), one launch --
__global__ __launch_bounds__(256)
void cvtall_k(const float* __restrict__ wq, const float* __restrict__ wk,
              const float* __restrict__ wv, const float* __restrict__ wproj,
              const float* __restrict__ w1, const float* __restrict__ w2,
              ushort* __restrict__ wqkvT, ushort* __restrict__ wpT,
              ushort* __restrict__ w1T, ushort* __restrict__ w2T)
{
    __shared__ float t[32][33];
    int idx = blockIdx.x;
    const float* src; ushort* dst; int R, Cc, bx, by;
    if (idx < 3072) {                      // wq/wk/wv: 3 x 16 heads x [1024][64]
        int seg = idx >> 10, rem = idx & 1023;
        int z = rem >> 6, tt2 = rem & 63;
        src = (seg == 0 ? wq : seg == 1 ? wk : wv) + (long)z * 65536;
        dst = wqkvT + (long)seg * (1L << 20) + (long)z * 65536;
        R = 1024; Cc = 64; bx = tt2 & 1; by = tt2 >> 1;
    } else if (idx < 4096) {               // w_proj [1024][1024]
        int tt2 = idx - 3072;
        src = wproj; dst = wpT; R = 1024; Cc = 1024; bx = tt2 & 31; by = tt2 >> 5;
    } else if (idx < 8192) {               // w1 [1024][4096]
        int tt2 = idx - 4096;
        src = w1; dst = w1T; R = 1024; Cc = 4096; bx = tt2 & 127; by = tt2 >> 7;
    } else {                               // w2 [4096][1024]
        int tt2 = idx - 8192;
        src = w2; dst = w2T; R = 4096; Cc = 1024; bx = tt2 & 31; by = tt2 >> 5;
    }
    int r0 = by * 32, c0 = bx * 32;
    int tx = threadIdx.x & 31, ty = threadIdx.x >> 5;
#pragma unroll
    for (int i = 0; i < 4; i++)
        t[ty + 8*i][tx] = src[(long)(r0 + ty + 8*i) * Cc + c0 + tx];
    __syncthreads();
#pragma unroll
    for (int i = 0; i < 4; i++)
        dst[(long)(c0 + ty + 8*i) * R + r0 + tx] = f2b(t[tx][ty + 8*i]);
}

// ---------------- bf16 MFMA GEMM ---------------------------------------------
enum { OL_PLAIN = 0, OL_QKV3 = 1 };
constexpr int EBIAS = 1, ERELU = 2, ERES = 4, ESCALE = 8;

template<int BM, int BN, int WM, int WN, int OL, int EPI, typename OutT>
__global__ __launch_bounds__(256)
void mgemm_k(const ushort* __restrict__ A, const ushort* __restrict__ Bt,
             const float* __restrict__ bias, const float* __restrict__ res,
             OutT* __restrict__ C, int M, int N, int K,
             long sA, long sB, long sC, float scale)
{
    constexpr int BK = 64;
    constexpr int FM = BM / WM / 16, FN = BN / WN / 16;
    __shared__ ushort As[BM * BK];
    __shared__ ushort Bs[BN * BK];
    const int tid = threadIdx.x;
    const int w = tid >> 6, l = tid & 63;
    const int wr = w / WN, wc = w % WN;
    const int l15 = l & 15, l4 = l >> 4;
    const int bh = blockIdx.z;
    const ushort* Ap = A  + (long)bh * sA + (long)(blockIdx.y * BM) * K;
    const ushort* Bp = Bt + (long)bh * sB + (long)(blockIdx.x * BN) * K;

    f32x4 acc[FM][FN];
#pragma unroll
    for (int m = 0; m < FM; m++)
#pragma unroll
        for (int n = 0; n < FN; n++) acc[m][n] = (f32x4){0.f, 0.f, 0.f, 0.f};

    const int arow = tid >> 3;
    const int achk = tid & 7;

    for (int k0 = 0; k0 < K; k0 += BK) {
#pragma unroll
        for (int i = 0; i < BM / 32; i++)
            gload16(Ap + (long)(i*32 + arow) * K + k0 + achk*8,
                    &As[(i*32 + w*8) * BK]);
#pragma unroll
        for (int i = 0; i < BN / 32; i++)
            gload16(Bp + (long)(i*32 + arow) * K + k0 + achk*8,
                    &Bs[(i*32 + w*8) * BK]);
        __syncthreads();
#pragma unroll
        for (int kk = 0; kk < 2; kk++) {
            const int ko = kk*32 + l4*8;
            bf16x8 af[FM], bfr[FN];
#pragma unroll
            for (int m = 0; m < FM; m++)
                af[m] = *(const bf16x8*)&As[(wr*(BM/WM) + m*16 + l15) * BK + ko];
#pragma unroll
            for (int n = 0; n < FN; n++)
                bfr[n] = *(const bf16x8*)&Bs[(wc*(BN/WN) + n*16 + l15) * BK + ko];
#pragma unroll
            for (int m = 0; m < FM; m++)
#pragma unroll
                for (int n = 0; n < FN; n++)
                    acc[m][n] = __builtin_amdgcn_mfma_f32_16x16x32_bf16(
                        af[m], bfr[n], acc[m][n], 0, 0, 0);
        }
        __syncthreads();
    }

#pragma unroll
    for (int m = 0; m < FM; m++) {
        int rbase = blockIdx.y*BM + wr*(BM/WM) + m*16 + l4*4;
#pragma unroll
        for (int n = 0; n < FN; n++) {
            int col = blockIdx.x*BN + wc*(BN/WN) + n*16 + l15;
#pragma unroll
            for (int r = 0; r < 4; r++) {
                int row = rbase + r;
                float v = acc[m][n][r];
                if (EPI & ESCALE) v *= scale;
                if (EPI & EBIAS)  v += bias[col];
                if (EPI & ERELU)  v = fmaxf(v, 0.f);
                if (EPI & ERES)   v += res[(long)row * N + col];
                long idx;
                if (OL == OL_PLAIN) {
                    idx = (long)row * N + col;
                } else {
                    // fused QKV: col segment 0=q,1=k,2=v(transposed)
                    int seg = col >> 10;
                    int cl  = col & 1023;
                    long bh_ = ((long)((row >> 10) * HH + (cl >> 6))) * 65536;
                    long off = (seg == 2)
                        ? bh_ + (long)(cl & 63) * 1024 + (row & 1023)
                        : bh_ + (long)(row & 1023) * 64 + (cl & 63);
                    idx = (long)seg * (4L << 20) + off;
                }
                stv(&C[(long)bh * sC + idx], v);
            }
        }
    }
}

// ---------------- Fused attention (no-max softmax; swizzled LDS) -------------
// LDS XOR-swizzle (rule #21): gload_lds dests stay linear; global SOURCE chunk
// is pre-swizzled (chunk ^= row&7 for 128B rows, ^= row&15 for 256B rows);
// every ds_read / Ps write applies the same XOR. Kills the 16-way row-stride
// bank conflicts on Qs/Ks (128B rows) and Vs/Ps (256B rows).
__global__ __launch_bounds__(256, 2)
void fattn_k(const ushort* __restrict__ q_, const ushort* __restrict__ k_,
             const ushort* __restrict__ vt, float* __restrict__ wei,
             ushort* __restrict__ attn)
{
    __shared__ ushort Qs[128*64];
    __shared__ ushort Ks[128*64];
    __shared__ ushort Vs[64*128];
    __shared__ ushort Ps[128*128];          // pass2 P tile; pass1-end reduce scratch
    float* sred = (float*)Ps;               // [2][128]

    const int tid = threadIdx.x;
    const int w = tid >> 6, l = tid & 63;
    const int wr = w >> 1, wc = w & 1;
    const int l15 = l & 15, l4 = l >> 4;
    const int bh = blockIdx.y;
    const int q0 = blockIdx.x * 128;
    const int arow = tid >> 3, achk = tid & 7;
    const int kchk = achk ^ (arow & 7);      // swizzled source chunk, 128B rows
    const int vrow = tid >> 4;               // 0..15
    const int vchk = (tid & 15) ^ (vrow & 15); // swizzled source chunk, 256B rows
    const int sw8  = (l15 & 7) << 3;         // read XOR (elements), 128B rows
    const int sw16 = l15 << 3;               // read XOR (elements), 256B rows

    const ushort* Qp = q_ + (long)bh * 65536;
    const ushort* Kp = k_ + (long)bh * 65536;
    const ushort* Vp = vt + (long)bh * 65536;

    // stage Q (persistent, swizzled source)
#pragma unroll
    for (int i = 0; i < 4; i++)
        gload16(Qp + (long)(q0 + i*32 + arow) * 64 + kchk*8, &Qs[(i*32 + w*8)*64]);

    float ssum[4][4];
#pragma unroll
    for (int m = 0; m < 4; m++)
#pragma unroll
        for (int r = 0; r < 4; r++) ssum[m][r] = 0.f;

    // ---- pass 1: row sums of exp(S) ----
    for (int st = 0; st < 8; ++st) {
#pragma unroll
        for (int i = 0; i < 4; i++)
            gload16(Kp + (long)(st*128 + i*32 + arow) * 64 + kchk*8,
                    &Ks[(i*32 + w*8)*64]);
        __syncthreads();

        f32x4 sacc[4][4];
#pragma unroll
        for (int m = 0; m < 4; m++)
#pragma unroll
            for (int n = 0; n < 4; n++) sacc[m][n] = (f32x4){0.f,0.f,0.f,0.f};
        __builtin_amdgcn_s_setprio(1);
#pragma unroll
        for (int kk = 0; kk < 2; kk++) {
            const int ko = kk*32 + l4*8;
            bf16x8 af[4], bfr[4];
#pragma unroll
            for (int m = 0; m < 4; m++)
                af[m] = *(const bf16x8*)&Qs[(wr*64 + m*16 + l15)*64 + (ko ^ sw8)];
#pragma unroll
            for (int n = 0; n < 4; n++)
                bfr[n] = *(const bf16x8*)&Ks[(wc*64 + n*16 + l15)*64 + (ko ^ sw8)];
#pragma unroll
            for (int m = 0; m < 4; m++)
#pragma unroll
                for (int n = 0; n < 4; n++)
                    sacc[m][n] = __builtin_amdgcn_mfma_f32_16x16x32_bf16(
                        af[m], bfr[n], sacc[m][n], 0, 0, 0);
        }
        __builtin_amdgcn_s_setprio(0);
#pragma unroll
        for (int m = 0; m < 4; m++)
#pragma unroll
            for (int r = 0; r < 4; r++) {
                float s = 0.f;
#pragma unroll
                for (int n = 0; n < 4; n++) s += __expf(sacc[m][n][r] * 0.125f);
                ssum[m][r] += s;
            }
        __syncthreads();   // Ks consumed before next stage
    }

    // final reduce: 16 lanes, then across wc via LDS
    float linv[4][4];
#pragma unroll
    for (int m = 0; m < 4; m++)
#pragma unroll
        for (int r = 0; r < 4; r++) {
            float s = ssum[m][r];
#pragma unroll
            for (int d = 1; d < 16; d <<= 1) s += __shfl_xor(s, d);
            ssum[m][r] = s;
            if (l15 == 0) sred[wc*128 + wr*64 + m*16 + l4*4 + r] = s;
        }
    __syncthreads();
#pragma unroll
    for (int m = 0; m < 4; m++)
#pragma unroll
        for (int r = 0; r < 4; r++) {
            int rg = wr*64 + m*16 + l4*4 + r;
            linv[m][r] = 1.0f / (sred[rg] + sred[128 + rg]);
        }
    __syncthreads();       // sred dead before Ps reuse

    // ---- pass 2: P + PV ----
    f32x4 oacc[4][2];
#pragma unroll
    for (int m = 0; m < 4; m++)
#pragma unroll
        for (int n = 0; n < 2; n++) oacc[m][n] = (f32x4){0.f,0.f,0.f,0.f};

    for (int st = 0; st < 8; ++st) {
#pragma unroll
        for (int i = 0; i < 4; i++)
            gload16(Kp + (long)(st*128 + i*32 + arow) * 64 + kchk*8,
                    &Ks[(i*32 + w*8)*64]);
#pragma unroll
        for (int i = 0; i < 4; i++)
            gload16(Vp + (long)(i*16 + vrow) * 1024 + st*128 + vchk*8,
                    &Vs[(i*16 + w*4)*128]);
        __syncthreads();

        f32x4 sacc[4][4];
#pragma unroll
        for (int m = 0; m < 4; m++)
#pragma unroll
            for (int n = 0; n < 4; n++) sacc[m][n] = (f32x4){0.f,0.f,0.f,0.f};
        __builtin_amdgcn_s_setprio(1);
#pragma unroll
        for (int kk = 0; kk < 2; kk++) {
            const int ko = kk*32 + l4*8;
            bf16x8 af[4], bfr[4];
#pragma unroll
            for (int m = 0; m < 4; m++)
                af[m] = *(const bf16x8*)&Qs[(wr*64 + m*16 + l15)*64 + (ko ^ sw8)];
#pragma unroll
            for (int n = 0; n < 4; n++)
                bfr[n] = *(const bf16x8*)&Ks[(wc*64 + n*16 + l15)*64 + (ko ^ sw8)];
#pragma unroll
            for (int m = 0; m < 4; m++)
#pragma unroll
                for (int n = 0; n < 4; n++)
                    sacc[m][n] = __builtin_amdgcn_mfma_f32_16x16x32_bf16(
                        af[m], bfr[n], sacc[m][n], 0, 0, 0);
        }
        __builtin_amdgcn_s_setprio(0);

        float* wrow = wei + (long)bh * (TT*(long)TT) + st*128;
#pragma unroll
        for (int m = 0; m < 4; m++)
#pragma unroll
            for (int r = 0; r < 4; r++) {
                int rg = wr*64 + m*16 + l4*4 + r;
                int psw = (rg & 15) << 3;
                float li = linv[m][r];
#pragma unroll
                for (int n = 0; n < 4; n++) {
                    int col = wc*64 + n*16 + l15;
                    float p = __expf(sacc[m][n][r] * 0.125f) * li;
                    __builtin_nontemporal_store(p, &wrow[(long)(q0 + rg) * TT + col]);
                    Ps[rg*128 + (col ^ psw)] = f2b(p);
                }
            }
        __syncthreads();

        // PV: O += P @ V (normalized P)
        __builtin_amdgcn_s_setprio(1);
#pragma unroll
        for (int kc = 0; kc < 4; ++kc) {
            const int ko = kc*32 + l4*8;
            bf16x8 pa[4], vb[2];
#pragma unroll
            for (int m = 0; m < 4; m++)
                pa[m] = *(const bf16x8*)&Ps[(wr*64 + m*16 + l15)*128 + (ko ^ sw16)];
#pragma unroll
            for (int n = 0; n < 2; n++)
                vb[n] = *(const bf16x8*)&Vs[(wc*32 + n*16 + l15)*128 + (ko ^ sw16)];
#pragma unroll
            for (int m = 0; m < 4; m++)
#pragma unroll
                for (int n = 0; n < 2; n++)
                    oacc[m][n] = __builtin_amdgcn_mfma_f32_16x16x32_bf16(
                        pa[m], vb[n], oacc[m][n], 0, 0, 0);
        }
        __builtin_amdgcn_s_setprio(0);
        __syncthreads();
    }

    // epilogue: attn [B,T,C] bf16
#pragma unroll
    for (int m = 0; m < 4; m++)
#pragma unroll
        for (int r = 0; r < 4; r++) {
            int rg = wr*64 + m*16 + l4*4 + r;
            long rowbase = ((long)(bh >> 4) * TT + q0 + rg) * CC + (long)(bh & 15) * HSZ;
#pragma unroll
            for (int n = 0; n < 2; n++)
                attn[rowbase + wc*32 + n*16 + l15] = f2b(oacc[m][n][r]);
        }
}

// ---------------- launch -----------------------------------------------------
extern "C" void kernel_launch(void* const* d_in, const int* in_sizes, int n_in,
                              void* d_out, int out_size, void* d_ws, size_t ws_size,
                              hipStream_t stream)
{
    const float* x      = (const float*)d_in[0];
    const float* wq     = (const float*)d_in[1];
    const float* wk     = (const float*)d_in[2];
    const float* wv     = (const float*)d_in[3];
    const float* w_proj = (const float*)d_in[4];
    const float* b_proj = (const float*)d_in[5];
    const float* w1     = (const float*)d_in[6];
    const float* b1     = (const float*)d_in[7];
    const float* w2     = (const float*)d_in[8];
    const float* b2     = (const float*)d_in[9];
    const float* g1     = (const float*)d_in[10];
    const float* be1    = (const float*)d_in[11];
    const float* g2     = (const float*)d_in[12];
    const float* be2    = (const float*)d_in[13];

    float* out_x = (float*)d_out;                  // [B,T,C]
    float* wei   = out_x + (long)NTOK * CC;        // [B,H,T,T] f32

    const long MEL = 1 << 20;
    ushort* ws16 = (ushort*)d_ws;
    ushort* h    = ws16;                 // [4096,1024] bf16 (LN1 out)
    ushort* q_   = ws16 + 4*MEL;         // [B,H,T,HS]   (k_ = q_+4M, vt = q_+8M)
    ushort* k_   = ws16 + 8*MEL;
    ushort* vt   = ws16 + 12*MEL;        // [B,H,HS,T]
    ushort* attn = ws16 + 16*MEL;        // [4096,1024] bf16
    ushort* h2   = ws16 + 20*MEL;        // [4096,1024] bf16 (LN2 out)
    ushort* a1   = ws16 + 24*MEL;        // [4096,4096] bf16
    ushort* wqkvT= ws16 + 40*MEL;        // [3072,1024] bf16 (q rows 0-1023, k, v)
    ushort* w1T  = ws16 + 44*MEL;        // [4096,1024]
    ushort* wpT  = ws16 + 48*MEL;        // [1024,1024]
    ushort* w2T  = ws16 + 49*MEL;        // [1024,4096]
    float*  x1   = (float*)(ws16 + 54*MEL);  // [4096,1024] f32

    // all weight conversions in one launch (12288 x 32x32 tiles)
    cvtall_k<<<12288, 256, 0, stream>>>(wq, wk, wv, w_proj, w1, w2,
                                        wqkvT, wpT, w1T, w2T);

    // 1. h = LN(x)
    ln_k<<<NTOK, 256, 0, stream>>>(x, g1, be1, h);

    // 2. fused q,k,v projection (N=3072)
    mgemm_k<128,128,2,2,OL_QKV3,0,ushort><<<dim3(24,32,1), 256, 0, stream>>>(
        h, wqkvT, nullptr, nullptr, q_, NTOK, 3072, CC, 0,0,0, 0.f);

    // 3-5. fused attention: wei (f32, d_out) + attn (bf16 headcat)
    fattn_k<<<dim3(8, 64), 256, 0, stream>>>(q_, k_, vt, wei, attn);

    // 6. x1 = x + attn @ w_proj + b_proj  (f32)
    mgemm_k<128,128,2,2,OL_PLAIN,EBIAS|ERES,float><<<dim3(8,32,1), 256, 0, stream>>>(
        attn, wpT, b_proj, x, x1, NTOK, CC, CC, 0,0,0, 0.f);

    // 7. h2 = LN(x1)
    ln_k<<<NTOK, 256, 0, stream>>>(x1, g2, be2, h2);

    // 8. a1 = relu(h2 @ w1 + b1)  bf16
    mgemm_k<128,128,2,2,OL_PLAIN,EBIAS|ERELU,ushort><<<dim3(32,32,1), 256, 0, stream>>>(
        h2, w1T, b1, nullptr, a1, NTOK, DFF, CC, 0,0,0, 0.f);

    // 9. out = x1 + a1 @ w2 + b2  (f32)
    mgemm_k<128,128,2,2,OL_PLAIN,EBIAS|ERES,float><<<dim3(8,32,1), 256, 0, stream>>>(
        a1, w2T, b2, x1, out_x, NTOK, CC, DFF, 0,0,0, 0.f);
}

// Round 6
// 369.377 us; speedup vs baseline: 8.9296x; 1.0322x over previous
//
#include <hip/hip_runtime.h>
#include <hip/hip_bf16.h>

// Problem constants
#define BB    4
#define TT    1024
#define CC    1024
#define HH    16
#define HSZ   64
#define DFF   4096
#define NTOK  (BB*TT)          // 4096
#define BHN   (BB*HH)          // 64

typedef __attribute__((ext_vector_type(8))) short bf16x8;
typedef __attribute__((ext_vector_type(4))) float f32x4;

#define VMC0 asm volatile("s_waitcnt vmcnt(0)" ::: "memory")
#define VMC4 asm volatile("s_waitcnt vmcnt(4)" ::: "memory")
#define LGK0 asm volatile("s_waitcnt lgkmcnt(0)" ::: "memory")
#define BARRIER do { asm volatile("" ::: "memory"); \
                     __builtin_amdgcn_s_barrier();  \
                     asm volatile("" ::: "memory"); } while (0)

__device__ __forceinline__ ushort f2b(float v) {
    union { float f; unsigned u; } c; c.f = v;
    unsigned r = c.u + 0x7fffu + ((c.u >> 16) & 1u);   // RNE
    return (ushort)(r >> 16);
}
__device__ __forceinline__ void stv(float* p, float v)  { *p = v; }
__device__ __forceinline__ void stv(ushort* p, float v) { *p = f2b(v); }

__device__ __forceinline__ void gload16(const void* g, void* l) {
    __builtin_amdgcn_global_load_lds(
        (const __attribute__((address_space(1))) void*)g,
        (__attribute__((address_space(3))) void*)l, 16, 0, 0);
}

// ---------------- LayerNorm: f32 in -> bf16 out ------------------------------
__global__ __launch_bounds__(256)
void ln_k(const float* __restrict__ x, const float* __restrict__ g,
          const float* __restrict__ be, ushort* __restrict__ o)
{
    __shared__ float s1[4], s2[4];
    long row = blockIdx.x;
    const float4* xr = (const float4*)(x + row * CC);
    float4 v = xr[threadIdx.x];
    float a = v.x + v.y + v.z + v.w;
    float b = v.x*v.x + v.y*v.y + v.z*v.z + v.w*v.w;
    for (int off = 32; off > 0; off >>= 1) {
        a += __shfl_down(a, off);
        b += __shfl_down(b, off);
    }
    if ((threadIdx.x & 63) == 0) { s1[threadIdx.x >> 6] = a; s2[threadIdx.x >> 6] = b; }
    __syncthreads();
    float sum = s1[0] + s1[1] + s1[2] + s1[3];
    float sq  = s2[0] + s2[1] + s2[2] + s2[3];
    float mu  = sum * (1.0f / CC);
    float var = sq * (1.0f / CC) - mu * mu;
    float inv = rsqrtf(var + 1e-5f);
    float4 gg = ((const float4*)g)[threadIdx.x];
    float4 bb = ((const float4*)be)[threadIdx.x];
    ushort4 r;
    r.x = f2b((v.x - mu) * inv * gg.x + bb.x);
    r.y = f2b((v.y - mu) * inv * gg.y + bb.y);
    r.z = f2b((v.z - mu) * inv * gg.z + bb.z);
    r.w = f2b((v.w - mu) * inv * gg.w + bb.w);
    ((ushort4*)(o + row * CC))[threadIdx.x] = r;
}

// ---------------- All weight conversions (transposed f32->bf16), one launch --
__global__ __launch_bounds__(256)
void cvtall_k(const float* __restrict__ wq, const float* __restrict__ wk,
              const float* __restrict__ wv, const float* __restrict__ wproj,
              const float* __restrict__ w1, const float* __restrict__ w2,
              ushort* __restrict__ wqkvT, ushort* __restrict__ wpT,
              ushort* __restrict__ w1T, ushort* __restrict__ w2T)
{
    __shared__ float t[32][33];
    int idx = blockIdx.x;
    const float* src; ushort* dst; int R, Cc, bx, by;
    if (idx < 3072) {                      // wq/wk/wv: 3 x 16 heads x [1024][64]
        int seg = idx >> 10, rem = idx & 1023;
        int z = rem >> 6, tt2 = rem & 63;
        src = (seg == 0 ? wq : seg == 1 ? wk : wv) + (long)z * 65536;
        dst = wqkvT + (long)seg * (1L << 20) + (long)z * 65536;
        R = 1024; Cc = 64; bx = tt2 & 1; by = tt2 >> 1;
    } else if (idx < 4096) {               // w_proj [1024][1024]
        int tt2 = idx - 3072;
        src = wproj; dst = wpT; R = 1024; Cc = 1024; bx = tt2 & 31; by = tt2 >> 5;
    } else if (idx < 8192) {               // w1 [1024][4096]
        int tt2 = idx - 4096;
        src = w1; dst = w1T; R = 1024; Cc = 4096; bx = tt2 & 127; by = tt2 >> 7;
    } else {                               // w2 [4096][1024]
        int tt2 = idx - 8192;
        src = w2; dst = w2T; R = 4096; Cc = 1024; bx = tt2 & 31; by = tt2 >> 5;
    }
    int r0 = by * 32, c0 = bx * 32;
    int tx = threadIdx.x & 31, ty = threadIdx.x >> 5;
#pragma unroll
    for (int i = 0; i < 4; i++)
        t[ty + 8*i][tx] = src[(long)(r0 + ty + 8*i) * Cc + c0 + tx];
    __syncthreads();
#pragma unroll
    for (int i = 0; i < 4; i++)
        dst[(long)(c0 + ty + 8*i) * R + r0 + tx] = f2b(t[tx][ty + 8*i]);
}

// ---------------- bf16 MFMA GEMM ---------------------------------------------
enum { OL_PLAIN = 0, OL_QKV3 = 1 };
constexpr int EBIAS = 1, ERELU = 2, ERES = 4, ESCALE = 8;

template<int BM, int BN, int WM, int WN, int OL, int EPI, typename OutT>
__global__ __launch_bounds__(256)
void mgemm_k(const ushort* __restrict__ A, const ushort* __restrict__ Bt,
             const float* __restrict__ bias, const float* __restrict__ res,
             OutT* __restrict__ C, int M, int N, int K,
             long sA, long sB, long sC, float scale)
{
    constexpr int BK = 64;
    constexpr int FM = BM / WM / 16, FN = BN / WN / 16;
    __shared__ ushort As[BM * BK];
    __shared__ ushort Bs[BN * BK];
    const int tid = threadIdx.x;
    const int w = tid >> 6, l = tid & 63;
    const int wr = w / WN, wc = w % WN;
    const int l15 = l & 15, l4 = l >> 4;
    const int bh = blockIdx.z;
    const ushort* Ap = A  + (long)bh * sA + (long)(blockIdx.y * BM) * K;
    const ushort* Bp = Bt + (long)bh * sB + (long)(blockIdx.x * BN) * K;

    f32x4 acc[FM][FN];
#pragma unroll
    for (int m = 0; m < FM; m++)
#pragma unroll
        for (int n = 0; n < FN; n++) acc[m][n] = (f32x4){0.f, 0.f, 0.f, 0.f};

    const int arow = tid >> 3;
    const int achk = tid & 7;

    for (int k0 = 0; k0 < K; k0 += BK) {
#pragma unroll
        for (int i = 0; i < BM / 32; i++)
            gload16(Ap + (long)(i*32 + arow) * K + k0 + achk*8,
                    &As[(i*32 + w*8) * BK]);
#pragma unroll
        for (int i = 0; i < BN / 32; i++)
            gload16(Bp + (long)(i*32 + arow) * K + k0 + achk*8,
                    &Bs[(i*32 + w*8) * BK]);
        __syncthreads();
#pragma unroll
        for (int kk = 0; kk < 2; kk++) {
            const int ko = kk*32 + l4*8;
            bf16x8 af[FM], bfr[FN];
#pragma unroll
            for (int m = 0; m < FM; m++)
                af[m] = *(const bf16x8*)&As[(wr*(BM/WM) + m*16 + l15) * BK + ko];
#pragma unroll
            for (int n = 0; n < FN; n++)
                bfr[n] = *(const bf16x8*)&Bs[(wc*(BN/WN) + n*16 + l15) * BK + ko];
#pragma unroll
            for (int m = 0; m < FM; m++)
#pragma unroll
                for (int n = 0; n < FN; n++)
                    acc[m][n] = __builtin_amdgcn_mfma_f32_16x16x32_bf16(
                        af[m], bfr[n], acc[m][n], 0, 0, 0);
        }
        __syncthreads();
    }

#pragma unroll
    for (int m = 0; m < FM; m++) {
        int rbase = blockIdx.y*BM + wr*(BM/WM) + m*16 + l4*4;
#pragma unroll
        for (int n = 0; n < FN; n++) {
            int col = blockIdx.x*BN + wc*(BN/WN) + n*16 + l15;
#pragma unroll
            for (int r = 0; r < 4; r++) {
                int row = rbase + r;
                float v = acc[m][n][r];
                if (EPI & ESCALE) v *= scale;
                if (EPI & EBIAS)  v += bias[col];
                if (EPI & ERELU)  v = fmaxf(v, 0.f);
                if (EPI & ERES)   v += res[(long)row * N + col];
                long idx;
                if (OL == OL_PLAIN) {
                    idx = (long)row * N + col;
                } else {
                    // fused QKV: col segment 0=q,1=k,2=v(transposed)
                    int seg = col >> 10;
                    int cl  = col & 1023;
                    long bh_ = ((long)((row >> 10) * HH + (cl >> 6))) * 65536;
                    long off = (seg == 2)
                        ? bh_ + (long)(cl & 63) * 1024 + (row & 1023)
                        : bh_ + (long)(row & 1023) * 64 + (cl & 63);
                    idx = (long)seg * (4L << 20) + off;
                }
                stv(&C[(long)bh * sC + idx], v);
            }
        }
    }
}

// ---------------- Fused attention (no-max softmax; swizzled LDS; pipelined) --
// Pass 1: K staging double-buffered across Ks/Vs (Vs idle in pass 1), raw
// s_barrier + counted vmcnt(4) -> next tile's loads stay in flight (T3/T4).
// Pass 2: raw barriers; lgkmcnt(0)-only before PV; wei stores issued AFTER
// the PV MFMA cluster (p kept in regs) so they overlap PV + next stage and
// are only drained by the next tile's single vmcnt(0).
__global__ __launch_bounds__(256, 2)
void fattn_k(const ushort* __restrict__ q_, const ushort* __restrict__ k_,
             const ushort* __restrict__ vt, float* __restrict__ wei,
             ushort* __restrict__ attn)
{
    __shared__ ushort Qs[128*64];
    __shared__ ushort Ks[128*64];
    __shared__ ushort Vs[64*128];           // pass1: K double-buffer half
    __shared__ ushort Ps[128*128];          // pass2 P tile; pass1-end reduce scratch
    float* sred = (float*)Ps;               // [2][128]

    const int tid = threadIdx.x;
    const int w = tid >> 6, l = tid & 63;
    const int wr = w >> 1, wc = w & 1;
    const int l15 = l & 15, l4 = l >> 4;
    const int bh = blockIdx.y;
    const int q0 = blockIdx.x * 128;
    const int arow = tid >> 3, achk = tid & 7;
    const int kchk = achk ^ (arow & 7);        // swizzled source chunk, 128B rows
    const int vrow = tid >> 4;                 // 0..15
    const int vchk = (tid & 15) ^ (vrow & 15); // swizzled source chunk, 256B rows
    const int sw8  = (l15 & 7) << 3;           // read XOR (elements), 128B rows
    const int sw16 = l15 << 3;                 // read XOR (elements), 256B rows

    const ushort* Qp = q_ + (long)bh * 65536;
    const ushort* Kp = k_ + (long)bh * 65536;
    const ushort* Vp = vt + (long)bh * 65536;

    // stage Q (persistent) + K tile 0 -> Ks
#pragma unroll
    for (int i = 0; i < 4; i++)
        gload16(Qp + (long)(q0 + i*32 + arow) * 64 + kchk*8, &Qs[(i*32 + w*8)*64]);
#pragma unroll
    for (int i = 0; i < 4; i++)
        gload16(Kp + (long)(i*32 + arow) * 64 + kchk*8, &Ks[(i*32 + w*8)*64]);

    float ssum[4][4];
#pragma unroll
    for (int m = 0; m < 4; m++)
#pragma unroll
        for (int r = 0; r < 4; r++) ssum[m][r] = 0.f;

    // ---- pass 1: row sums of exp(S); double-buffered K (Ks <-> Vs) ----
    for (int st = 0; st < 8; ++st) {
        const ushort* cur = (st & 1) ? Vs : Ks;
        ushort*       nxt = (st & 1) ? Ks : Vs;
        if (st < 7) {
#pragma unroll
            for (int i = 0; i < 4; i++)
                gload16(Kp + (long)((st+1)*128 + i*32 + arow) * 64 + kchk*8,
                        &nxt[(i*32 + w*8)*64]);
            VMC4;          // own current-tile loads done; next-tile 4 in flight
        } else {
            VMC0;
        }
        BARRIER;           // all waves staged current tile

        f32x4 sacc[4][4];
#pragma unroll
        for (int m = 0; m < 4; m++)
#pragma unroll
            for (int n = 0; n < 4; n++) sacc[m][n] = (f32x4){0.f,0.f,0.f,0.f};
        __builtin_amdgcn_s_setprio(1);
#pragma unroll
        for (int kk = 0; kk < 2; kk++) {
            const int ko = kk*32 + l4*8;
            bf16x8 af[4], bfr[4];
#pragma unroll
            for (int m = 0; m < 4; m++)
                af[m] = *(const bf16x8*)&Qs[(wr*64 + m*16 + l15)*64 + (ko ^ sw8)];
#pragma unroll
            for (int n = 0; n < 4; n++)
                bfr[n] = *(const bf16x8*)&cur[(wc*64 + n*16 + l15)*64 + (ko ^ sw8)];
#pragma unroll
            for (int m = 0; m < 4; m++)
#pragma unroll
                for (int n = 0; n < 4; n++)
                    sacc[m][n] = __builtin_amdgcn_mfma_f32_16x16x32_bf16(
                        af[m], bfr[n], sacc[m][n], 0, 0, 0);
        }
        __builtin_amdgcn_s_setprio(0);
#pragma unroll
        for (int m = 0; m < 4; m++)
#pragma unroll
            for (int r = 0; r < 4; r++) {
                float s = 0.f;
#pragma unroll
                for (int n = 0; n < 4; n++) s += __expf(sacc[m][n][r] * 0.125f);
                ssum[m][r] += s;
            }
        BARRIER;           // cur consumed by all waves before it's restaged
    }

    // prefetch pass-2 tile 0 (K0 -> Ks, V0 -> Vs) under the reduction
#pragma unroll
    for (int i = 0; i < 4; i++)
        gload16(Kp + (long)(i*32 + arow) * 64 + kchk*8, &Ks[(i*32 + w*8)*64]);
#pragma unroll
    for (int i = 0; i < 4; i++)
        gload16(Vp + (long)(i*16 + vrow) * 1024 + vchk*8, &Vs[(i*16 + w*4)*128]);

    // final reduce: 16 lanes, then across wc via LDS (sred lives in Ps)
    float linv[4][4];
#pragma unroll
    for (int m = 0; m < 4; m++)
#pragma unroll
        for (int r = 0; r < 4; r++) {
            float s = ssum[m][r];
#pragma unroll
            for (int d = 1; d < 16; d <<= 1) s += __shfl_xor(s, d);
            if (l15 == 0) sred[wc*128 + wr*64 + m*16 + l4*4 + r] = s;
        }
    LGK0; BARRIER;
#pragma unroll
    for (int m = 0; m < 4; m++)
#pragma unroll
        for (int r = 0; r < 4; r++) {
            int rg = wr*64 + m*16 + l4*4 + r;
            linv[m][r] = 1.0f / (sred[rg] + sred[128 + rg]);
        }

    // ---- pass 2: P + PV ----
    f32x4 oacc[4][2];
#pragma unroll
    for (int m = 0; m < 4; m++)
#pragma unroll
        for (int n = 0; n < 2; n++) oacc[m][n] = (f32x4){0.f,0.f,0.f,0.f};

    for (int st = 0; st < 8; ++st) {
        if (st > 0) {
#pragma unroll
            for (int i = 0; i < 4; i++)
                gload16(Kp + (long)(st*128 + i*32 + arow) * 64 + kchk*8,
                        &Ks[(i*32 + w*8)*64]);
#pragma unroll
            for (int i = 0; i < 4; i++)
                gload16(Vp + (long)(i*16 + vrow) * 1024 + st*128 + vchk*8,
                        &Vs[(i*16 + w*4)*128]);
        }
        VMC0;              // stage done (also drains prev tile's wei stores)
        BARRIER;

        f32x4 sacc[4][4];
#pragma unroll
        for (int m = 0; m < 4; m++)
#pragma unroll
            for (int n = 0; n < 4; n++) sacc[m][n] = (f32x4){0.f,0.f,0.f,0.f};
        __builtin_amdgcn_s_setprio(1);
#pragma unroll
        for (int kk = 0; kk < 2; kk++) {
            const int ko = kk*32 + l4*8;
            bf16x8 af[4], bfr[4];
#pragma unroll
            for (int m = 0; m < 4; m++)
                af[m] = *(const bf16x8*)&Qs[(wr*64 + m*16 + l15)*64 + (ko ^ sw8)];
#pragma unroll
            for (int n = 0; n < 4; n++)
                bfr[n] = *(const bf16x8*)&Ks[(wc*64 + n*16 + l15)*64 + (ko ^ sw8)];
#pragma unroll
            for (int m = 0; m < 4; m++)
#pragma unroll
                for (int n = 0; n < 4; n++)
                    sacc[m][n] = __builtin_amdgcn_mfma_f32_16x16x32_bf16(
                        af[m], bfr[n], sacc[m][n], 0, 0, 0);
        }
        __builtin_amdgcn_s_setprio(0);

        // exp + Ps write; keep normalized p in regs for the deferred wei store
        float pv[4][4][4];
#pragma unroll
        for (int m = 0; m < 4; m++)
#pragma unroll
            for (int r = 0; r < 4; r++) {
                int rg = wr*64 + m*16 + l4*4 + r;
                int psw = (rg & 15) << 3;
                float li = linv[m][r];
#pragma unroll
                for (int n = 0; n < 4; n++) {
                    int col = wc*64 + n*16 + l15;
                    float p = __expf(sacc[m][n][r] * 0.125f) * li;
                    pv[m][n][r] = p;
                    Ps[rg*128 + (col ^ psw)] = f2b(p);
                }
            }
        LGK0; BARRIER;     // Ps visible to all waves (no vmcnt drain)

        // PV: O += P @ V (normalized P)
        __builtin_amdgcn_s_setprio(1);
#pragma unroll
        for (int kc = 0; kc < 4; ++kc) {
            const int ko = kc*32 + l4*8;
            bf16x8 pa[4], vb[2];
#pragma unroll
            for (int m = 0; m < 4; m++)
                pa[m] = *(const bf16x8*)&Ps[(wr*64 + m*16 + l15)*128 + (ko ^ sw16)];
#pragma unroll
            for (int n = 0; n < 2; n++)
                vb[n] = *(const bf16x8*)&Vs[(wc*32 + n*16 + l15)*128 + (ko ^ sw16)];
#pragma unroll
            for (int m = 0; m < 4; m++)
#pragma unroll
                for (int n = 0; n < 2; n++)
                    oacc[m][n] = __builtin_amdgcn_mfma_f32_16x16x32_bf16(
                        pa[m], vb[n], oacc[m][n], 0, 0, 0);
        }
        __builtin_amdgcn_s_setprio(0);

        // deferred wei stores: overlap PV tail + next tile's staging
        float* wrow = wei + (long)bh * (TT*(long)TT) + st*128;
#pragma unroll
        for (int m = 0; m < 4; m++)
#pragma unroll
            for (int r = 0; r < 4; r++) {
                int rg = wr*64 + m*16 + l4*4 + r;
#pragma unroll
                for (int n = 0; n < 4; n++) {
                    int col = wc*64 + n*16 + l15;
                    __builtin_nontemporal_store(pv[m][n][r],
                        &wrow[(long)(q0 + rg) * TT + col]);
                }
            }
        BARRIER;           // Ks/Vs/Ps reusable next tile (stores stay in flight)
    }

    // epilogue: attn [B,T,C] bf16
#pragma unroll
    for (int m = 0; m < 4; m++)
#pragma unroll
        for (int r = 0; r < 4; r++) {
            int rg = wr*64 + m*16 + l4*4 + r;
            long rowbase = ((long)(bh >> 4) * TT + q0 + rg) * CC + (long)(bh & 15) * HSZ;
#pragma unroll
            for (int n = 0; n < 2; n++)
                attn[rowbase + wc*32 + n*16 + l15] = f2b(oacc[m][n][r]);
        }
}

// ---------------- launch -----------------------------------------------------
extern "C" void kernel_launch(void* const* d_in, const int* in_sizes, int n_in,
                              void* d_out, int out_size, void* d_ws, size_t ws_size,
                              hipStream_t stream)
{
    const float* x      = (const float*)d_in[0];
    const float* wq     = (const float*)d_in[1];
    const float* wk     = (const float*)d_in[2];
    const float* wv     = (const float*)d_in[3];
    const float* w_proj = (const float*)d_in[4];
    const float* b_proj = (const float*)d_in[5];
    const float* w1     = (const float*)d_in[6];
    const float* b1     = (const float*)d_in[7];
    const float* w2     = (const float*)d_in[8];
    const float* b2     = (const float*)d_in[9];
    const float* g1     = (const float*)d_in[10];
    const float* be1    = (const float*)d_in[11];
    const float* g2     = (const float*)d_in[12];
    const float* be2    = (const float*)d_in[13];

    float* out_x = (float*)d_out;                  // [B,T,C]
    float* wei   = out_x + (long)NTOK * CC;        // [B,H,T,T] f32

    const long MEL = 1 << 20;
    ushort* ws16 = (ushort*)d_ws;
    ushort* h    = ws16;                 // [4096,1024] bf16 (LN1 out)
    ushort* q_   = ws16 + 4*MEL;         // [B,H,T,HS]   (k_ = q_+4M, vt = q_+8M)
    ushort* k_   = ws16 + 8*MEL;
    ushort* vt   = ws16 + 12*MEL;        // [B,H,HS,T]
    ushort* attn = ws16 + 16*MEL;        // [4096,1024] bf16
    ushort* h2   = ws16 + 20*MEL;        // [4096,1024] bf16 (LN2 out)
    ushort* a1   = ws16 + 24*MEL;        // [4096,4096] bf16
    ushort* wqkvT= ws16 + 40*MEL;        // [3072,1024] bf16 (q rows 0-1023, k, v)
    ushort* w1T  = ws16 + 44*MEL;        // [4096,1024]
    ushort* wpT  = ws16 + 48*MEL;        // [1024,1024]
    ushort* w2T  = ws16 + 49*MEL;        // [1024,4096]
    float*  x1   = (float*)(ws16 + 54*MEL);  // [4096,1024] f32

    // all weight conversions in one launch (12288 x 32x32 tiles)
    cvtall_k<<<12288, 256, 0, stream>>>(wq, wk, wv, w_proj, w1, w2,
                                        wqkvT, wpT, w1T, w2T);

    // 1. h = LN(x)
    ln_k<<<NTOK, 256, 0, stream>>>(x, g1, be1, h);

    // 2. fused q,k,v projection (N=3072)
    mgemm_k<128,128,2,2,OL_QKV3,0,ushort><<<dim3(24,32,1), 256, 0, stream>>>(
        h, wqkvT, nullptr, nullptr, q_, NTOK, 3072, CC, 0,0,0, 0.f);

    // 3-5. fused attention: wei (f32, d_out) + attn (bf16 headcat)
    fattn_k<<<dim3(8, 64), 256, 0, stream>>>(q_, k_, vt, wei, attn);

    // 6. x1 = x + attn @ w_proj + b_proj  (f32)
    mgemm_k<128,128,2,2,OL_PLAIN,EBIAS|ERES,float><<<dim3(8,32,1), 256, 0, stream>>>(
        attn, wpT, b_proj, x, x1, NTOK, CC, CC, 0,0,0, 0.f);

    // 7. h2 = LN(x1)
    ln_k<<<NTOK, 256, 0, stream>>>(x1, g2, be2, h2);

    // 8. a1 = relu(h2 @ w1 + b1)  bf16
    mgemm_k<128,128,2,2,OL_PLAIN,EBIAS|ERELU,ushort><<<dim3(32,32,1), 256, 0, stream>>>(
        h2, w1T, b1, nullptr, a1, NTOK, DFF, CC, 0,0,0, 0.f);

    // 9. out = x1 + a1 @ w2 + b2  (f32)
    mgemm_k<128,128,2,2,OL_PLAIN,EBIAS|ERES,float><<<dim3(8,32,1), 256, 0, stream>>>(
        a1, w2T, b2, x1, out_x, NTOK, CC, DFF, 0,0,0, 0.f);
}